// Round 4
// baseline (415.158 us; speedup 1.0000x reference)
//
#include <hip/hip_runtime.h>
#include <hip/hip_bf16.h>

#define D 128
#define NPBK 256    // nodes per coarse bucket (partition/placement)
#define NBMAX 512   // max coarse buckets supported by LDS arrays
#define TILE_A 4096 // edges per partition block (256 thr x 16)

typedef unsigned int uint;
typedef unsigned short ushort;
typedef __attribute__((ext_vector_type(8))) short short8;
typedef __attribute__((ext_vector_type(4))) float f32x4;

// unpack a bf16x2 (as uint) into two floats: x = low half, y = high half
static __device__ __forceinline__ float2 bf16x2(uint u) {
  float2 r;
  r.x = __uint_as_float(u << 16);
  r.y = __uint_as_float(u & 0xffff0000u);
  return r;
}

static __device__ __forceinline__ uint pack_bf16x2(float a, float b) {
  __hip_bfloat162 o;
  o.x = __float2bfloat16(a);
  o.y = __float2bfloat16(b);
  return *reinterpret_cast<uint*>(&o);
}

static __device__ __forceinline__ ushort f2bf(float f) {
  __hip_bfloat16 h = __float2bfloat16(f);
  return *reinterpret_cast<ushort*>(&h);
}
static __device__ __forceinline__ float bf2f(ushort u) {
  return __uint_as_float(((uint)u) << 16);
}

// accumulate 8 bf16 values (packed in a uint4) into acc[0..7]
static __device__ __forceinline__ void acc8(float* acc, uint4 v) {
  float2 t0 = bf16x2(v.x), t1 = bf16x2(v.y);
  float2 t2 = bf16x2(v.z), t3 = bf16x2(v.w);
  acc[0] += t0.x; acc[1] += t0.y;
  acc[2] += t1.x; acc[3] += t1.y;
  acc[4] += t2.x; acc[5] += t2.y;
  acc[6] += t3.x; acc[7] += t3.y;
}

// ---------------------------------------------------------------------------
// Detect input dtype (bf16 vs fp32 storage). flag=1 means fp32.
// ---------------------------------------------------------------------------
__global__ void detect_kernel(const uint* __restrict__ x, int n_words,
                              int* __restrict__ flag) {
  __shared__ float smax[256];
  float m = 0.f;
  for (int i = threadIdx.x; i < n_words; i += 256) {
    float2 v = bf16x2(x[i]);
    float a = fabsf(v.x), b = fabsf(v.y);
    if (!(a <= 1e30f)) a = 1e30f;
    if (!(b <= 1e30f)) b = 1e30f;
    m = fmaxf(m, fmaxf(a, b));
  }
  smax[threadIdx.x] = m;
  __syncthreads();
  for (int s = 128; s > 0; s >>= 1) {
    if (threadIdx.x < s)
      smax[threadIdx.x] = fmaxf(smax[threadIdx.x], smax[threadIdx.x + s]);
    __syncthreads();
  }
  if (threadIdx.x == 0) *flag = (smax[0] > 1e6f) ? 1 : 0;
}

// ---------------------------------------------------------------------------
// Histogram of edge destinations: deg (PPI col), cnt (DTI prot)
// ---------------------------------------------------------------------------
__global__ void count_kernel(const int* __restrict__ ppi_col,
                             const int* __restrict__ dti_prot,
                             int* __restrict__ deg, int* __restrict__ cnt,
                             int e_ppi, int e_dti, int n_prot) {
  int i = blockIdx.x * blockDim.x + threadIdx.x;
  if (i < e_ppi) {
    int c = ppi_col[i];
    if ((unsigned)c < (unsigned)n_prot) atomicAdd(&deg[c], 1);
  } else if (i < e_ppi + e_dti) {
    int c = dti_prot[i - e_ppi];
    if ((unsigned)c < (unsigned)n_prot) atomicAdd(&cnt[c], 1);
  }
}

// ---------------------------------------------------------------------------
// Per-node normalizers + per-scan-block sums (fused)
// ---------------------------------------------------------------------------
__global__ void block_sum_kernel(const int* __restrict__ deg,
                                 const int* __restrict__ cnt, int n,
                                 float* __restrict__ dinv,
                                 float* __restrict__ invcnt,
                                 int* __restrict__ bsum) {
  __shared__ int sh[256];
  int i = blockIdx.x * 256 + threadIdx.x;
  int t = 0;
  if (i < n) {
    int d = deg[i], c = cnt[i];
    dinv[i] = rsqrtf((float)(d + 1));  // +1 self-loop
    invcnt[i] = 1.0f / fmaxf((float)c, 1.0f);
    t = d + c;
  }
  sh[threadIdx.x] = t;
  __syncthreads();
  for (int s = 128; s > 0; s >>= 1) {
    if (threadIdx.x < s) sh[threadIdx.x] += sh[threadIdx.x + s];
    __syncthreads();
  }
  if (threadIdx.x == 0) bsum[blockIdx.x] = sh[0];
}

// single block: in-place exclusive scan of bsum[0..nb)
__global__ void scan_bsums_kernel(int* __restrict__ bsum, int nb) {
  __shared__ int sh[1024];
  __shared__ int carry;
  int tid = threadIdx.x;
  if (tid == 0) carry = 0;
  __syncthreads();
  for (int base = 0; base < nb; base += 1024) {
    int i = base + tid;
    int v = (i < nb) ? bsum[i] : 0;
    sh[tid] = v;
    __syncthreads();
    for (int ofs = 1; ofs < 1024; ofs <<= 1) {
      int t = (tid >= ofs) ? sh[tid - ofs] : 0;
      __syncthreads();
      sh[tid] += t;
      __syncthreads();
    }
    if (i < nb) bsum[i] = carry + sh[tid] - v;  // exclusive
    int total = sh[1023];
    __syncthreads();
    if (tid == 0) carry += total;
    __syncthreads();
  }
}

// final scan + writes coarse-bucket cursors (bcur[b] = offsets[b*NPBK])
__global__ void scan_final_kernel(const int* __restrict__ deg,
                                  const int* __restrict__ cnt,
                                  const int* __restrict__ bbase,
                                  int* __restrict__ offsets,
                                  int* __restrict__ bcur, int n) {
  __shared__ int sh[256];
  int tid = threadIdx.x;
  int i = blockIdx.x * 256 + tid;
  int v = (i < n) ? deg[i] + cnt[i] : 0;
  sh[tid] = v;
  __syncthreads();
  for (int ofs = 1; ofs < 256; ofs <<= 1) {
    int t = (tid >= ofs) ? sh[tid - ofs] : 0;
    __syncthreads();
    sh[tid] += t;
    __syncthreads();
  }
  if (i < n) {
    int excl = bbase[blockIdx.x] + sh[tid] - v;
    offsets[i] = excl;
    if (tid == 0) bcur[blockIdx.x] = excl;  // NPBK == 256 == block size
    if (i == n - 1) offsets[n] = excl + v;
  }
}

// ---------------------------------------------------------------------------
// Fallback CSR fill (only used when packing guards fail).
// ---------------------------------------------------------------------------
__global__ void fill_kernel(const int* __restrict__ ppi_row,
                            const int* __restrict__ ppi_col,
                            const int* __restrict__ dti_drug,
                            const int* __restrict__ dti_prot,
                            const int* __restrict__ offsets,
                            const int* __restrict__ deg,
                            int* __restrict__ fposp, int* __restrict__ fposd,
                            uint* __restrict__ csr, int e_ppi, int e_dti,
                            int n_prot) {
  int i = blockIdx.x * blockDim.x + threadIdx.x;
  if (i < e_ppi) {
    int dst = ppi_col[i];
    if ((unsigned)dst >= (unsigned)n_prot) return;
    int pos = offsets[dst] + atomicAdd(&fposp[dst], 1);
    csr[pos] = (uint)ppi_row[i];
  } else if (i < e_ppi + e_dti) {
    int j = i - e_ppi;
    int dst = dti_prot[j];
    if ((unsigned)dst >= (unsigned)n_prot) return;
    int pos = offsets[dst] + deg[dst] + atomicAdd(&fposd[dst], 1);
    csr[pos] = (uint)dti_drug[j];
  }
}

// ---------------------------------------------------------------------------
// Pass A: partition edges into coarse dst-buckets (256 nodes each).
// Packed entry: src(17b) | type(1b)<<17 | (dst&255)<<18  -> one uint.
// ---------------------------------------------------------------------------
__global__ __launch_bounds__(256) void partition_kernel(
    const int* __restrict__ ppi_row, const int* __restrict__ ppi_col,
    const int* __restrict__ dti_drug, const int* __restrict__ dti_prot,
    int* __restrict__ bcur, uint* __restrict__ P, int e_ppi, int e_dti,
    int n_prot, int nb) {
  __shared__ int hist[NBMAX];
  __shared__ int cur[NBMAX];
  const int tid = threadIdx.x;
  const int base = blockIdx.x * TILE_A;
  const int e_tot = e_ppi + e_dti;

  for (int b = tid; b < nb; b += 256) hist[b] = 0;
  __syncthreads();

  uint sv[16];
  int dv[16];
#pragma unroll
  for (int j = 0; j < 16; ++j) {
    int i = base + j * 256 + tid;
    int d = -1;
    uint s = 0;
    if (i < e_tot) {
      int src, dst, type;
      if (i < e_ppi) {
        src = ppi_row[i];
        dst = ppi_col[i];
        type = 0;
      } else {
        int k = i - e_ppi;
        src = dti_drug[k];
        dst = dti_prot[k];
        type = 1;
      }
      if ((unsigned)dst < (unsigned)n_prot) {
        d = dst;
        s = (uint)src | ((uint)type << 17);
        atomicAdd(&hist[dst >> 8], 1);
      }
    }
    sv[j] = s;
    dv[j] = d;
  }
  __syncthreads();

  for (int b = tid; b < nb; b += 256) {
    int h = hist[b];
    cur[b] = h ? atomicAdd(&bcur[b], h) : 0;
  }
  __syncthreads();

#pragma unroll
  for (int j = 0; j < 16; ++j) {
    if (dv[j] >= 0) {
      int b = dv[j] >> 8;
      int r = atomicAdd(&cur[b], 1);
      P[r] = sv[j] | ((uint)(dv[j] & (NPBK - 1)) << 18);
    }
  }
}

// ---------------------------------------------------------------------------
// Pass B: one block per bucket, 1024 threads (16 waves) for latency hiding.
// Per-node cursors in LDS; CSR writes confined to a ~24KB L2-resident window.
// ---------------------------------------------------------------------------
__global__ __launch_bounds__(1024) void place_kernel(
    const uint* __restrict__ P, const int* __restrict__ offsets,
    const int* __restrict__ deg, uint* __restrict__ csr, int n_prot) {
  __shared__ int cp[NPBK];
  __shared__ int cd[NPBK];
  const int tid = threadIdx.x;
  const int node0 = blockIdx.x * NPBK;
  const int nn = min(NPBK, n_prot - node0);
  if (tid < nn) {
    int o = offsets[node0 + tid];
    cp[tid] = o;
    cd[tid] = o + deg[node0 + tid];
  }
  __syncthreads();
  const int start = offsets[node0];
  const int end = offsets[node0 + nn];
  for (int i = start + tid; i < end; i += 1024) {
    uint p = P[i];
    uint src = p & 0x1ffffu;
    int nl = (int)(p >> 18);
    int pos = ((p >> 17) & 1u) ? atomicAdd(&cd[nl], 1) : atomicAdd(&cp[nl], 1);
    csr[pos] = src;
  }
}

// ---------------------------------------------------------------------------
// MFMA dual-output protein GEMM, 512 threads = 8 waves, 64 rows per iter.
//   g = x_prot[row] @ W_gcn  -> xw2[row] = bf16(g * dinv[row])
//   outx3[row] = x_prot[row] @ W_pr + (b_gcn+b_pr+1e-6) + dinv^2 * g
// fp32 x handled via hi/lo bf16 split (x = hi + lo).
// ---------------------------------------------------------------------------
__global__ __launch_bounds__(512) void gemm_prot_mfma(
    const void* __restrict__ X, const void* __restrict__ Wg,
    const void* __restrict__ Wp, const void* __restrict__ bg,
    const void* __restrict__ bp, const float* __restrict__ dinv,
    uint* __restrict__ xw2, void* __restrict__ outx3,
    const int* __restrict__ flag, int M) {
  __shared__ uint4 aF[4][4][2][64];  // [rowgrp][ktile][hi/lo][lane] : 32 KB
  __shared__ ushort xwl[64][128];    // transpose buffer for xw2 : 16 KB
  const int isf = *flag;
  const int tid = threadIdx.x;
  const int wv = tid >> 6, lane = tid & 63;
  const int cl = lane & 15, kg = lane >> 4;
  const int c = wv * 16 + cl;  // this wave's output column (0..127)

  short8 bG[4], bP[4];
#pragma unroll
  for (int kt = 0; kt < 4; ++kt) {
    int k0 = kt * 32 + 8 * kg;
    short8 fg, fp;
    if (isf) {
      const float* WgF = (const float*)Wg;
      const float* WpF = (const float*)Wp;
#pragma unroll
      for (int j = 0; j < 8; ++j) {
        fg[j] = (short)f2bf(WgF[(k0 + j) * D + c]);
        fp[j] = (short)f2bf(WpF[(k0 + j) * D + c]);
      }
    } else {
      const ushort* WgH = (const ushort*)Wg;
      const ushort* WpH = (const ushort*)Wp;
#pragma unroll
      for (int j = 0; j < 8; ++j) {
        fg[j] = (short)WgH[(k0 + j) * D + c];
        fp[j] = (short)WpH[(k0 + j) * D + c];
      }
    }
    bG[kt] = fg;
    bP[kt] = fp;
  }
  float btc;
  {
    float a = isf ? ((const float*)bg)[c] : bf2f(((const ushort*)bg)[c]);
    float b = isf ? ((const float*)bp)[c] : bf2f(((const ushort*)bp)[c]);
    btc = a + b + 1e-6f;
  }

  for (int row0 = blockIdx.x * 64; row0 < M; row0 += gridDim.x * 64) {
    for (int u = tid; u < 1024; u += 512) {
      int row = u >> 4, kc = u & 15;
      int grow = row0 + row;
      uint4 hi = make_uint4(0, 0, 0, 0), lo = make_uint4(0, 0, 0, 0);
      if (isf) {
        if (grow < M) {
          const float4* Xf = (const float4*)X;
          float4 v0 = Xf[(size_t)grow * 32 + kc * 2];
          float4 v1 = Xf[(size_t)grow * 32 + kc * 2 + 1];
          float v[8] = {v0.x, v0.y, v0.z, v0.w, v1.x, v1.y, v1.z, v1.w};
          uint hw[4], lw[4];
#pragma unroll
          for (int j = 0; j < 4; ++j) {
            ushort h0 = f2bf(v[2 * j]), h1 = f2bf(v[2 * j + 1]);
            ushort l0 = f2bf(v[2 * j] - bf2f(h0));
            ushort l1 = f2bf(v[2 * j + 1] - bf2f(h1));
            hw[j] = (uint)h0 | ((uint)h1 << 16);
            lw[j] = (uint)l0 | ((uint)l1 << 16);
          }
          hi = make_uint4(hw[0], hw[1], hw[2], hw[3]);
          lo = make_uint4(lw[0], lw[1], lw[2], lw[3]);
        }
      } else {
        if (grow < M) hi = ((const uint4*)X)[(size_t)grow * 16 + kc];
      }
      int ln = (kc & 3) * 16 + (row & 15);
      int g = row >> 4, kt = kc >> 2;
      aF[g][kt][0][ln] = hi;
      if (isf) aF[g][kt][1][ln] = lo;
    }
    __syncthreads();

#pragma unroll
    for (int g = 0; g < 4; ++g) {
      f32x4 accG = {0.f, 0.f, 0.f, 0.f};
      f32x4 accP = {0.f, 0.f, 0.f, 0.f};
      uint4 aH[4];
#pragma unroll
      for (int kt = 0; kt < 4; ++kt) aH[kt] = aF[g][kt][0][lane];
#pragma unroll
      for (int kt = 0; kt < 4; ++kt) {
        short8 a = __builtin_bit_cast(short8, aH[kt]);
        accG = __builtin_amdgcn_mfma_f32_16x16x32_bf16(a, bG[kt], accG, 0, 0, 0);
        accP = __builtin_amdgcn_mfma_f32_16x16x32_bf16(a, bP[kt], accP, 0, 0, 0);
      }
      if (isf) {
        uint4 aL[4];
#pragma unroll
        for (int kt = 0; kt < 4; ++kt) aL[kt] = aF[g][kt][1][lane];
#pragma unroll
        for (int kt = 0; kt < 4; ++kt) {
          short8 a = __builtin_bit_cast(short8, aL[kt]);
          accG = __builtin_amdgcn_mfma_f32_16x16x32_bf16(a, bG[kt], accG, 0, 0, 0);
          accP = __builtin_amdgcn_mfma_f32_16x16x32_bf16(a, bP[kt], accP, 0, 0, 0);
        }
      }
      int rl0 = g * 16 + kg * 4;
#pragma unroll
      for (int r = 0; r < 4; ++r) {
        int row = row0 + rl0 + r;
        if (row < M) {
          float dn = dinv[row];
          float gv = accG[r], pv = accP[r];
          xwl[rl0 + r][c] = f2bf(gv * dn);
          float ov = fmaf(gv, dn * dn, pv + btc);
          if (isf)
            ((float*)outx3)[(size_t)row * D + c] = ov;
          else
            ((ushort*)outx3)[(size_t)row * D + c] = f2bf(ov);
        }
      }
    }
    __syncthreads();

    int valid = min(64, M - row0);
    const uint4* src = (const uint4*)xwl;
    uint4* dst = (uint4*)xw2 + (size_t)row0 * 16;
    for (int u = tid; u < valid * 16; u += 512) dst[u] = src[u];
  }
}

// ---------------------------------------------------------------------------
// MFMA drug GEMM: yd2[M][64] bf16 pairs = x_drug @ W_td + b_td
// ---------------------------------------------------------------------------
__global__ __launch_bounds__(512) void gemm_drug_mfma(
    const void* __restrict__ X, const void* __restrict__ W,
    const void* __restrict__ bias, uint* __restrict__ Y2,
    const int* __restrict__ flag, int M) {
  __shared__ uint4 aF[4][4][2][64];  // 32 KB
  __shared__ ushort yl[64][128];     // 16 KB
  const int isf = *flag;
  const int tid = threadIdx.x;
  const int wv = tid >> 6, lane = tid & 63;
  const int cl = lane & 15, kg = lane >> 4;
  const int c = wv * 16 + cl;

  short8 bT[4];
#pragma unroll
  for (int kt = 0; kt < 4; ++kt) {
    int k0 = kt * 32 + 8 * kg;
    short8 ft;
    if (isf) {
      const float* Wf = (const float*)W;
#pragma unroll
      for (int j = 0; j < 8; ++j) ft[j] = (short)f2bf(Wf[(k0 + j) * D + c]);
    } else {
      const ushort* Wh = (const ushort*)W;
#pragma unroll
      for (int j = 0; j < 8; ++j) ft[j] = (short)Wh[(k0 + j) * D + c];
    }
    bT[kt] = ft;
  }
  float btc = isf ? ((const float*)bias)[c] : bf2f(((const ushort*)bias)[c]);

  for (int row0 = blockIdx.x * 64; row0 < M; row0 += gridDim.x * 64) {
    for (int u = tid; u < 1024; u += 512) {
      int row = u >> 4, kc = u & 15;
      int grow = row0 + row;
      uint4 hi = make_uint4(0, 0, 0, 0), lo = make_uint4(0, 0, 0, 0);
      if (isf) {
        if (grow < M) {
          const float4* Xf = (const float4*)X;
          float4 v0 = Xf[(size_t)grow * 32 + kc * 2];
          float4 v1 = Xf[(size_t)grow * 32 + kc * 2 + 1];
          float v[8] = {v0.x, v0.y, v0.z, v0.w, v1.x, v1.y, v1.z, v1.w};
          uint hw[4], lw[4];
#pragma unroll
          for (int j = 0; j < 4; ++j) {
            ushort h0 = f2bf(v[2 * j]), h1 = f2bf(v[2 * j + 1]);
            ushort l0 = f2bf(v[2 * j] - bf2f(h0));
            ushort l1 = f2bf(v[2 * j + 1] - bf2f(h1));
            hw[j] = (uint)h0 | ((uint)h1 << 16);
            lw[j] = (uint)l0 | ((uint)l1 << 16);
          }
          hi = make_uint4(hw[0], hw[1], hw[2], hw[3]);
          lo = make_uint4(lw[0], lw[1], lw[2], lw[3]);
        }
      } else {
        if (grow < M) hi = ((const uint4*)X)[(size_t)grow * 16 + kc];
      }
      int ln = (kc & 3) * 16 + (row & 15);
      int g = row >> 4, kt = kc >> 2;
      aF[g][kt][0][ln] = hi;
      if (isf) aF[g][kt][1][ln] = lo;
    }
    __syncthreads();

#pragma unroll
    for (int g = 0; g < 4; ++g) {
      f32x4 acc = {0.f, 0.f, 0.f, 0.f};
      uint4 aH[4];
#pragma unroll
      for (int kt = 0; kt < 4; ++kt) aH[kt] = aF[g][kt][0][lane];
#pragma unroll
      for (int kt = 0; kt < 4; ++kt) {
        short8 a = __builtin_bit_cast(short8, aH[kt]);
        acc = __builtin_amdgcn_mfma_f32_16x16x32_bf16(a, bT[kt], acc, 0, 0, 0);
      }
      if (isf) {
        uint4 aL[4];
#pragma unroll
        for (int kt = 0; kt < 4; ++kt) aL[kt] = aF[g][kt][1][lane];
#pragma unroll
        for (int kt = 0; kt < 4; ++kt) {
          short8 a = __builtin_bit_cast(short8, aL[kt]);
          acc = __builtin_amdgcn_mfma_f32_16x16x32_bf16(a, bT[kt], acc, 0, 0, 0);
        }
      }
      int rl0 = g * 16 + kg * 4;
#pragma unroll
      for (int r = 0; r < 4; ++r) {
        int row = row0 + rl0 + r;
        if (row < M) yl[rl0 + r][c] = f2bf(acc[r] + btc);
      }
    }
    __syncthreads();

    int valid = min(64, M - row0);
    const uint4* src = (const uint4*)yl;
    uint4* dst = (uint4*)Y2 + (size_t)row0 * 16;
    for (int u = tid; u < valid * 16; u += 512) dst[u] = src[u];
  }
}

// ---------------------------------------------------------------------------
// Gather + LayerNorm. One wave per node; four 16-lane groups each gather one
// edge row as 16B dwordx4 (4 edges per VMEM instruction slot).
// ---------------------------------------------------------------------------
__global__ __launch_bounds__(256) void gather_ln_kernel(
    const uint* __restrict__ xw2, const uint* __restrict__ yd2,
    const float* __restrict__ dinv, const float* __restrict__ invcnt,
    const int* __restrict__ offsets, const int* __restrict__ deg,
    const uint* __restrict__ csr, void* __restrict__ out,
    const int* __restrict__ flag, int n_prot) {
  const int isf = *flag;
  const int node = (blockIdx.x * 256 + threadIdx.x) >> 6;
  const int lane = threadIdx.x & 63;
  const int grp = lane >> 4;  // 0..3 : edge sub-group
  const int li = lane & 15;   // cols [li*8, li*8+8)  (uint4 index li)
  if (node >= n_prot) return;
  const int s0 = offsets[node];
  const int s1 = offsets[node + 1];
  const int sm = s0 + deg[node];
  const float dn = dinv[node], ic = invcnt[node];

  float aP[8] = {0.f, 0.f, 0.f, 0.f, 0.f, 0.f, 0.f, 0.f};
  float aD[8] = {0.f, 0.f, 0.f, 0.f, 0.f, 0.f, 0.f, 0.f};

  const uint4* X4 = (const uint4*)xw2;
  const uint4* Y4 = (const uint4*)yd2;

#pragma unroll
  for (int part = 0; part < 2; ++part) {
    const uint4* T = part ? Y4 : X4;
    float* acc = part ? aD : aP;
    int a = part ? sm : s0;
    int b = part ? s1 : sm;
    for (int base = a; base < b;) {
      int m = min(64, b - base);
      uint ent = (lane < m) ? csr[base + lane] : 0u;
      int nb4 = m >> 2;
      int t = 0;
      for (; t + 4 <= nb4; t += 4) {  // 16 edges, 4 loads in flight per lane
        uint e0 = __shfl(ent, (t + 0) * 4 + grp);
        uint e1 = __shfl(ent, (t + 1) * 4 + grp);
        uint e2 = __shfl(ent, (t + 2) * 4 + grp);
        uint e3 = __shfl(ent, (t + 3) * 4 + grp);
        uint4 w0 = T[(size_t)e0 * 16 + li];
        uint4 w1 = T[(size_t)e1 * 16 + li];
        uint4 w2 = T[(size_t)e2 * 16 + li];
        uint4 w3 = T[(size_t)e3 * 16 + li];
        acc8(acc, w0);
        acc8(acc, w1);
        acc8(acc, w2);
        acc8(acc, w3);
      }
      for (; t < nb4; ++t) {
        uint e = __shfl(ent, t * 4 + grp);
        uint4 w = T[(size_t)e * 16 + li];
        acc8(acc, w);
      }
      int rem = m & 3;
      if (rem) {
        uint e = __shfl(ent, nb4 * 4 + grp);
        if (grp < rem) {
          uint4 w = T[(size_t)e * 16 + li];
          acc8(acc, w);
        }
      }
      base += m;
    }
  }

  // combine lists, reduce across the 4 groups (lanes ^16, ^32)
  float v[8];
#pragma unroll
  for (int i = 0; i < 8; ++i) v[i] = fmaf(dn, aP[i], ic * aD[i]);
#pragma unroll
  for (int i = 0; i < 8; ++i) {
    v[i] += __shfl_xor(v[i], 16);
    v[i] += __shfl_xor(v[i], 32);
  }

  // add x3' (read from out, in output dtype)
  if (isf) {
    const float4* xr = (const float4*)out + (size_t)node * 32 + li * 2;
    float4 x0 = xr[0], x1 = xr[1];
    v[0] += x0.x; v[1] += x0.y; v[2] += x0.z; v[3] += x0.w;
    v[4] += x1.x; v[5] += x1.y; v[6] += x1.z; v[7] += x1.w;
  } else {
    uint4 xr = ((const uint4*)out)[(size_t)node * 16 + li];
    float2 t0 = bf16x2(xr.x), t1 = bf16x2(xr.y);
    float2 t2 = bf16x2(xr.z), t3 = bf16x2(xr.w);
    v[0] += t0.x; v[1] += t0.y; v[2] += t1.x; v[3] += t1.y;
    v[4] += t2.x; v[5] += t2.y; v[6] += t3.x; v[7] += t3.y;
  }

  // LayerNorm over 128 cols (each li owns 8; reduce over 16 lanes)
  float s = 0.f, ss = 0.f;
#pragma unroll
  for (int i = 0; i < 8; ++i) {
    s += v[i];
    ss = fmaf(v[i], v[i], ss);
  }
#pragma unroll
  for (int off = 1; off < 16; off <<= 1) {
    s += __shfl_xor(s, off);
    ss += __shfl_xor(ss, off);
  }
  float mu = s * (1.0f / 128.0f);
  float var = ss * (1.0f / 128.0f) - mu * mu;
  float rs = rsqrtf(var + 1e-5f);
#pragma unroll
  for (int i = 0; i < 8; ++i) v[i] = (v[i] - mu) * rs;

  if (isf) {
    if (grp < 2) {  // 32 lanes cover the 512B row
      float4 o = (grp == 0) ? make_float4(v[0], v[1], v[2], v[3])
                            : make_float4(v[4], v[5], v[6], v[7]);
      ((float4*)out)[(size_t)node * 32 + li * 2 + grp] = o;
    }
  } else {
    if (grp == 0) {
      uint4 o;
      o.x = pack_bf16x2(v[0], v[1]);
      o.y = pack_bf16x2(v[2], v[3]);
      o.z = pack_bf16x2(v[4], v[5]);
      o.w = pack_bf16x2(v[6], v[7]);
      ((uint4*)out)[(size_t)node * 16 + li] = o;
    }
  }
}

// ---------------------------------------------------------------------------
extern "C" void kernel_launch(void* const* d_in, const int* in_sizes, int n_in,
                              void* d_out, int out_size, void* d_ws,
                              size_t ws_size, hipStream_t stream) {
  const void* x_prot = d_in[0];
  const void* x_drug = d_in[1];
  const void* W_gcn = d_in[2];
  const void* b_gcn = d_in[3];
  const void* W_td = d_in[4];
  const void* b_td = d_in[5];
  const void* W_pr = d_in[6];
  const void* b_pr = d_in[7];
  const int* ppi = (const int*)d_in[8];
  const int* dti_drug = (const int*)d_in[9];
  const int* dti_prot = (const int*)d_in[10];

  int n_prot = in_sizes[0] / D;
  int n_drug = in_sizes[1] / D;
  int e_ppi = in_sizes[8] / 2;
  int e_dti = in_sizes[9];
  int e_tot = e_ppi + e_dti;
  int nb = (n_prot + 255) / 256;
  int nbk = (n_prot + NPBK - 1) / NPBK;  // coarse buckets (== nb here)

  char* ws = (char*)d_ws;
  size_t off = 0;
  auto alloc = [&](size_t bytes) {
    void* p = ws + off;
    off = (off + bytes + 255) & ~(size_t)255;
    return p;
  };
  int* flag = (int*)alloc(256);
  uint* xw2 = (uint*)alloc((size_t)n_prot * 64 * 4);  // 25.6 MB (pre-scaled)
  uint* yd2 = (uint*)alloc((size_t)n_drug * 64 * 4);  //  5.1 MB
  int* deg = (int*)alloc((size_t)n_prot * 4);
  int* cnt = (int*)alloc((size_t)n_prot * 4);
  float* dinv = (float*)alloc((size_t)n_prot * 4);
  float* invcnt = (float*)alloc((size_t)n_prot * 4);
  int* offsets = (int*)alloc((size_t)(n_prot + 1) * 4);
  int* fposp = (int*)alloc((size_t)n_prot * 4);
  int* fposd = (int*)alloc((size_t)n_prot * 4);
  int* bsum = (int*)alloc((size_t)nb * 4);
  int* bcur = (int*)alloc((size_t)nbk * 4);
  uint* csr = (uint*)alloc((size_t)e_tot * 4);  // 9.6 MB

  if (off > ws_size) return;  // insufficient workspace: bail cleanly

  // Partitioned-edge scratch aliases xw2: place_kernel finishes before
  // gemm_prot_mfma writes xw2 (same stream), and e_tot*4 <= n_prot*256 here.
  uint* P = xw2;
  bool fast_fill = (n_prot <= (1 << 17)) && (n_drug <= (1 << 17)) &&
                   (nbk <= NBMAX) && ((size_t)e_tot * 4 <= (size_t)n_prot * 256);

  detect_kernel<<<1, 256, 0, stream>>>((const uint*)x_prot, 4096, flag);

  // deg and cnt are adjacent allocations: zero both with one memset
  hipMemsetAsync(deg, 0, (size_t)((char*)cnt - (char*)deg) + (size_t)n_prot * 4,
                 stream);

  count_kernel<<<(e_tot + 255) / 256, 256, 0, stream>>>(
      ppi + e_ppi, dti_prot, deg, cnt, e_ppi, e_dti, n_prot);

  block_sum_kernel<<<nb, 256, 0, stream>>>(deg, cnt, n_prot, dinv, invcnt,
                                           bsum);
  scan_bsums_kernel<<<1, 1024, 0, stream>>>(bsum, nb);
  scan_final_kernel<<<nb, 256, 0, stream>>>(deg, cnt, bsum, offsets, bcur,
                                            n_prot);

  if (fast_fill) {
    partition_kernel<<<(e_tot + TILE_A - 1) / TILE_A, 256, 0, stream>>>(
        ppi, ppi + e_ppi, dti_drug, dti_prot, bcur, P, e_ppi, e_dti, n_prot,
        nbk);
    place_kernel<<<nbk, 1024, 0, stream>>>(P, offsets, deg, csr, n_prot);
  } else {
    hipMemsetAsync(fposp, 0, (size_t)n_prot * 4, stream);
    hipMemsetAsync(fposd, 0, (size_t)n_prot * 4, stream);
    fill_kernel<<<(e_tot + 255) / 256, 256, 0, stream>>>(
        ppi, ppi + e_ppi, dti_drug, dti_prot, offsets, deg, fposp, fposd, csr,
        e_ppi, e_dti, n_prot);
  }

  int nbat_p = (n_prot + 63) / 64;
  int grid_p = nbat_p < 512 ? nbat_p : 512;
  gemm_prot_mfma<<<grid_p, 512, 0, stream>>>(x_prot, W_gcn, W_pr, b_gcn, b_pr,
                                             dinv, xw2, d_out, flag, n_prot);
  int nbat_d = (n_drug + 63) / 64;
  int grid_d = nbat_d < 512 ? nbat_d : 512;
  gemm_drug_mfma<<<grid_d, 512, 0, stream>>>(x_drug, W_td, b_td, yd2, flag,
                                             n_drug);

  gather_ln_kernel<<<(n_prot + 3) / 4, 256, 0, stream>>>(
      xw2, yd2, dinv, invcnt, offsets, deg, csr, d_out, flag, n_prot);
}

// Round 5
// 333.402 us; speedup vs baseline: 1.2452x; 1.2452x over previous
//
#include <hip/hip_runtime.h>
#include <hip/hip_bf16.h>

#define D 128
#define NPBK 256    // nodes per coarse bucket (partition/placement)
#define NBMAX 512   // max coarse buckets supported by LDS arrays
#define TILE_A 4096 // edges per partition block (256 thr x 16)

typedef unsigned int uint;
typedef unsigned short ushort;
typedef __attribute__((ext_vector_type(8))) short short8;
typedef __attribute__((ext_vector_type(4))) float f32x4;

// unpack a bf16x2 (as uint) into two floats: x = low half, y = high half
static __device__ __forceinline__ float2 bf16x2(uint u) {
  float2 r;
  r.x = __uint_as_float(u << 16);
  r.y = __uint_as_float(u & 0xffff0000u);
  return r;
}

static __device__ __forceinline__ uint pack_bf16x2(float a, float b) {
  __hip_bfloat162 o;
  o.x = __float2bfloat16(a);
  o.y = __float2bfloat16(b);
  return *reinterpret_cast<uint*>(&o);
}

static __device__ __forceinline__ ushort f2bf(float f) {
  __hip_bfloat16 h = __float2bfloat16(f);
  return *reinterpret_cast<ushort*>(&h);
}
static __device__ __forceinline__ float bf2f(ushort u) {
  return __uint_as_float(((uint)u) << 16);
}

// accumulate 8 bf16 values (packed in a uint4) into acc[0..7]
static __device__ __forceinline__ void acc8(float* acc, uint4 v) {
  float2 t0 = bf16x2(v.x), t1 = bf16x2(v.y);
  float2 t2 = bf16x2(v.z), t3 = bf16x2(v.w);
  acc[0] += t0.x; acc[1] += t0.y;
  acc[2] += t1.x; acc[3] += t1.y;
  acc[4] += t2.x; acc[5] += t2.y;
  acc[6] += t3.x; acc[7] += t3.y;
}

// ---------------------------------------------------------------------------
// Detect input dtype (bf16 vs fp32 storage). flag=1 means fp32.
// ---------------------------------------------------------------------------
__global__ void detect_kernel(const uint* __restrict__ x, int n_words,
                              int* __restrict__ flag) {
  __shared__ float smax[256];
  float m = 0.f;
  for (int i = threadIdx.x; i < n_words; i += 256) {
    float2 v = bf16x2(x[i]);
    float a = fabsf(v.x), b = fabsf(v.y);
    if (!(a <= 1e30f)) a = 1e30f;
    if (!(b <= 1e30f)) b = 1e30f;
    m = fmaxf(m, fmaxf(a, b));
  }
  smax[threadIdx.x] = m;
  __syncthreads();
  for (int s = 128; s > 0; s >>= 1) {
    if (threadIdx.x < s)
      smax[threadIdx.x] = fmaxf(smax[threadIdx.x], smax[threadIdx.x + s]);
    __syncthreads();
  }
  if (threadIdx.x == 0) *flag = (smax[0] > 1e6f) ? 1 : 0;
}

// ---------------------------------------------------------------------------
// FAST PATH pass 0: coarse bucket histogram (LDS) -> global bucket totals.
// One global atomic per (block,bucket) instead of per edge.
// ---------------------------------------------------------------------------
__global__ __launch_bounds__(256) void bucket_hist_kernel(
    const int* __restrict__ ppi_col, const int* __restrict__ dti_prot,
    int* __restrict__ gbh, int e_ppi, int e_dti, int n_prot, int nbk) {
  __shared__ int hist[NBMAX];
  const int tid = threadIdx.x;
  for (int b = tid; b < nbk; b += 256) hist[b] = 0;
  __syncthreads();
  const int e_tot = e_ppi + e_dti;
  const int base = blockIdx.x * 8192;
#pragma unroll 4
  for (int j = 0; j < 32; ++j) {
    int i = base + j * 256 + tid;
    if (i < e_tot) {
      int dst = (i < e_ppi) ? ppi_col[i] : dti_prot[i - e_ppi];
      if ((unsigned)dst < (unsigned)n_prot) atomicAdd(&hist[dst >> 8], 1);
    }
  }
  __syncthreads();
  for (int b = tid; b < nbk; b += 256) {
    int h = hist[b];
    if (h) atomicAdd(&gbh[b], h);
  }
}

// single block (NBMAX threads): exclusive scan of bucket totals -> bbase,
// and init allocation cursors bcur.
__global__ __launch_bounds__(NBMAX) void bucket_scan_kernel(
    const int* __restrict__ gbh, int* __restrict__ bbase,
    int* __restrict__ bcur, int nbk) {
  __shared__ int sh[NBMAX];
  const int tid = threadIdx.x;
  int v = (tid < nbk) ? gbh[tid] : 0;
  sh[tid] = v;
  __syncthreads();
  for (int ofs = 1; ofs < NBMAX; ofs <<= 1) {
    int t = (tid >= ofs) ? sh[tid - ofs] : 0;
    __syncthreads();
    sh[tid] += t;
    __syncthreads();
  }
  if (tid < nbk) {
    int e = sh[tid] - v;  // exclusive
    bbase[tid] = e;
    bcur[tid] = e;
    if (tid == nbk - 1) bbase[nbk] = sh[tid];
  }
}

// ---------------------------------------------------------------------------
// FAST PATH pass A: partition edges into coarse dst-buckets (256 nodes each).
// Packed entry: src(17b) | type(1b)<<17 | (dst&255)<<18  -> one uint.
// ---------------------------------------------------------------------------
__global__ __launch_bounds__(256) void partition_kernel(
    const int* __restrict__ ppi_row, const int* __restrict__ ppi_col,
    const int* __restrict__ dti_drug, const int* __restrict__ dti_prot,
    int* __restrict__ bcur, uint* __restrict__ P, int e_ppi, int e_dti,
    int n_prot, int nb) {
  __shared__ int hist[NBMAX];
  __shared__ int cur[NBMAX];
  const int tid = threadIdx.x;
  const int base = blockIdx.x * TILE_A;
  const int e_tot = e_ppi + e_dti;

  for (int b = tid; b < nb; b += 256) hist[b] = 0;
  __syncthreads();

  uint sv[16];
  int dv[16];
#pragma unroll
  for (int j = 0; j < 16; ++j) {
    int i = base + j * 256 + tid;
    int d = -1;
    uint s = 0;
    if (i < e_tot) {
      int src, dst, type;
      if (i < e_ppi) {
        src = ppi_row[i];
        dst = ppi_col[i];
        type = 0;
      } else {
        int k = i - e_ppi;
        src = dti_drug[k];
        dst = dti_prot[k];
        type = 1;
      }
      if ((unsigned)dst < (unsigned)n_prot) {
        d = dst;
        s = (uint)src | ((uint)type << 17);
        atomicAdd(&hist[dst >> 8], 1);
      }
    }
    sv[j] = s;
    dv[j] = d;
  }
  __syncthreads();

  for (int b = tid; b < nb; b += 256) {
    int h = hist[b];
    cur[b] = h ? atomicAdd(&bcur[b], h) : 0;
  }
  __syncthreads();

#pragma unroll
  for (int j = 0; j < 16; ++j) {
    if (dv[j] >= 0) {
      int b = dv[j] >> 8;
      int r = atomicAdd(&cur[b], 1);
      P[r] = sv[j] | ((uint)(dv[j] & (NPBK - 1)) << 18);
    }
  }
}

// ---------------------------------------------------------------------------
// FAST PATH pass B (fused): one block per bucket.
//  1) per-node deg/cnt histogram in LDS (no global atomics)
//  2) LDS scan -> per-node offsets; write deg/dinv/invcnt/offsets sequentially
//  3) place CSR entries via LDS cursors (writes confined to L2-hot window)
// Replaces count/block_sum/scan_bsums/scan_final/place of the old pipeline.
// ---------------------------------------------------------------------------
__global__ __launch_bounds__(1024) void place_count_kernel(
    const uint* __restrict__ P, const int* __restrict__ bbase,
    uint* __restrict__ csr, int* __restrict__ deg, float* __restrict__ dinv,
    float* __restrict__ invcnt, int* __restrict__ offsets, int n_prot,
    int nbk) {
  __shared__ int degL[NPBK], cntL[NPBK];
  __shared__ int cp[NPBK], cd[NPBK];
  __shared__ int sc[NPBK];
  const int tid = threadIdx.x;
  const int b = blockIdx.x;
  const int node0 = b * NPBK;
  const int nn = min(NPBK, n_prot - node0);
  const int start = bbase[b], end = bbase[b + 1];

  if (tid < NPBK) {
    degL[tid] = 0;
    cntL[tid] = 0;
  }
  __syncthreads();

  for (int i = start + tid; i < end; i += 1024) {
    uint p = P[i];
    int nl = (int)(p >> 18);
    if ((p >> 17) & 1u)
      atomicAdd(&cntL[nl], 1);
    else
      atomicAdd(&degL[nl], 1);
  }
  __syncthreads();

  // inclusive scan over per-node totals (256 entries)
  int v = 0;
  if (tid < NPBK) {
    v = (tid < nn) ? (degL[tid] + cntL[tid]) : 0;
    sc[tid] = v;
  }
  __syncthreads();
  for (int ofs = 1; ofs < NPBK; ofs <<= 1) {
    int t = 0;
    if (tid < NPBK && tid >= ofs) t = sc[tid - ofs];
    __syncthreads();
    if (tid < NPBK) sc[tid] += t;
    __syncthreads();
  }
  if (tid < nn) {
    int d = degL[tid], c = cntL[tid];
    int excl = start + sc[tid] - v;
    int node = node0 + tid;
    offsets[node] = excl;
    deg[node] = d;
    dinv[node] = rsqrtf((float)(d + 1));  // +1 self-loop
    invcnt[node] = 1.0f / fmaxf((float)c, 1.0f);
    cp[tid] = excl;
    cd[tid] = excl + d;
  }
  if (b == nbk - 1 && tid == 0) offsets[n_prot] = end;
  __syncthreads();

  for (int i = start + tid; i < end; i += 1024) {
    uint p = P[i];
    uint src = p & 0x1ffffu;
    int nl = (int)(p >> 18);
    int pos = ((p >> 17) & 1u) ? atomicAdd(&cd[nl], 1) : atomicAdd(&cp[nl], 1);
    csr[pos] = src;
  }
}

// ---------------------------------------------------------------------------
// FALLBACK path kernels (used only when packing guards fail).
// ---------------------------------------------------------------------------
__global__ void count_kernel(const int* __restrict__ ppi_col,
                             const int* __restrict__ dti_prot,
                             int* __restrict__ deg, int* __restrict__ cnt,
                             int e_ppi, int e_dti, int n_prot) {
  int i = blockIdx.x * blockDim.x + threadIdx.x;
  if (i < e_ppi) {
    int c = ppi_col[i];
    if ((unsigned)c < (unsigned)n_prot) atomicAdd(&deg[c], 1);
  } else if (i < e_ppi + e_dti) {
    int c = dti_prot[i - e_ppi];
    if ((unsigned)c < (unsigned)n_prot) atomicAdd(&cnt[c], 1);
  }
}

__global__ void block_sum_kernel(const int* __restrict__ deg,
                                 const int* __restrict__ cnt, int n,
                                 float* __restrict__ dinv,
                                 float* __restrict__ invcnt,
                                 int* __restrict__ bsum) {
  __shared__ int sh[256];
  int i = blockIdx.x * 256 + threadIdx.x;
  int t = 0;
  if (i < n) {
    int d = deg[i], c = cnt[i];
    dinv[i] = rsqrtf((float)(d + 1));  // +1 self-loop
    invcnt[i] = 1.0f / fmaxf((float)c, 1.0f);
    t = d + c;
  }
  sh[threadIdx.x] = t;
  __syncthreads();
  for (int s = 128; s > 0; s >>= 1) {
    if (threadIdx.x < s) sh[threadIdx.x] += sh[threadIdx.x + s];
    __syncthreads();
  }
  if (threadIdx.x == 0) bsum[blockIdx.x] = sh[0];
}

__global__ void scan_bsums_kernel(int* __restrict__ bsum, int nb) {
  __shared__ int sh[1024];
  __shared__ int carry;
  int tid = threadIdx.x;
  if (tid == 0) carry = 0;
  __syncthreads();
  for (int base = 0; base < nb; base += 1024) {
    int i = base + tid;
    int v = (i < nb) ? bsum[i] : 0;
    sh[tid] = v;
    __syncthreads();
    for (int ofs = 1; ofs < 1024; ofs <<= 1) {
      int t = (tid >= ofs) ? sh[tid - ofs] : 0;
      __syncthreads();
      sh[tid] += t;
      __syncthreads();
    }
    if (i < nb) bsum[i] = carry + sh[tid] - v;  // exclusive
    int total = sh[1023];
    __syncthreads();
    if (tid == 0) carry += total;
    __syncthreads();
  }
}

__global__ void scan_final_kernel(const int* __restrict__ deg,
                                  const int* __restrict__ cnt,
                                  const int* __restrict__ bbase,
                                  int* __restrict__ offsets, int n) {
  __shared__ int sh[256];
  int tid = threadIdx.x;
  int i = blockIdx.x * 256 + tid;
  int v = (i < n) ? deg[i] + cnt[i] : 0;
  sh[tid] = v;
  __syncthreads();
  for (int ofs = 1; ofs < 256; ofs <<= 1) {
    int t = (tid >= ofs) ? sh[tid - ofs] : 0;
    __syncthreads();
    sh[tid] += t;
    __syncthreads();
  }
  if (i < n) {
    int excl = bbase[blockIdx.x] + sh[tid] - v;
    offsets[i] = excl;
    if (i == n - 1) offsets[n] = excl + v;
  }
}

__global__ void fill_kernel(const int* __restrict__ ppi_row,
                            const int* __restrict__ ppi_col,
                            const int* __restrict__ dti_drug,
                            const int* __restrict__ dti_prot,
                            const int* __restrict__ offsets,
                            const int* __restrict__ deg,
                            int* __restrict__ fposp, int* __restrict__ fposd,
                            uint* __restrict__ csr, int e_ppi, int e_dti,
                            int n_prot) {
  int i = blockIdx.x * blockDim.x + threadIdx.x;
  if (i < e_ppi) {
    int dst = ppi_col[i];
    if ((unsigned)dst >= (unsigned)n_prot) return;
    int pos = offsets[dst] + atomicAdd(&fposp[dst], 1);
    csr[pos] = (uint)ppi_row[i];
  } else if (i < e_ppi + e_dti) {
    int j = i - e_ppi;
    int dst = dti_prot[j];
    if ((unsigned)dst >= (unsigned)n_prot) return;
    int pos = offsets[dst] + deg[dst] + atomicAdd(&fposd[dst], 1);
    csr[pos] = (uint)dti_drug[j];
  }
}

// ---------------------------------------------------------------------------
// MFMA dual-output protein GEMM, 512 threads = 8 waves, 64 rows per iter.
//   g = x_prot[row] @ W_gcn  -> xw2[row] = bf16(g * dinv[row])
//   outx3[row] = x_prot[row] @ W_pr + (b_gcn+b_pr+1e-6) + dinv^2 * g
// fp32 x handled via hi/lo bf16 split (x = hi + lo).
// ---------------------------------------------------------------------------
__global__ __launch_bounds__(512) void gemm_prot_mfma(
    const void* __restrict__ X, const void* __restrict__ Wg,
    const void* __restrict__ Wp, const void* __restrict__ bg,
    const void* __restrict__ bp, const float* __restrict__ dinv,
    uint* __restrict__ xw2, void* __restrict__ outx3,
    const int* __restrict__ flag, int M) {
  __shared__ uint4 aF[4][4][2][64];  // [rowgrp][ktile][hi/lo][lane] : 32 KB
  __shared__ ushort xwl[64][128];    // transpose buffer for xw2 : 16 KB
  const int isf = *flag;
  const int tid = threadIdx.x;
  const int wv = tid >> 6, lane = tid & 63;
  const int cl = lane & 15, kg = lane >> 4;
  const int c = wv * 16 + cl;  // this wave's output column (0..127)

  short8 bG[4], bP[4];
#pragma unroll
  for (int kt = 0; kt < 4; ++kt) {
    int k0 = kt * 32 + 8 * kg;
    short8 fg, fp;
    if (isf) {
      const float* WgF = (const float*)Wg;
      const float* WpF = (const float*)Wp;
#pragma unroll
      for (int j = 0; j < 8; ++j) {
        fg[j] = (short)f2bf(WgF[(k0 + j) * D + c]);
        fp[j] = (short)f2bf(WpF[(k0 + j) * D + c]);
      }
    } else {
      const ushort* WgH = (const ushort*)Wg;
      const ushort* WpH = (const ushort*)Wp;
#pragma unroll
      for (int j = 0; j < 8; ++j) {
        fg[j] = (short)WgH[(k0 + j) * D + c];
        fp[j] = (short)WpH[(k0 + j) * D + c];
      }
    }
    bG[kt] = fg;
    bP[kt] = fp;
  }
  float btc;
  {
    float a = isf ? ((const float*)bg)[c] : bf2f(((const ushort*)bg)[c]);
    float b = isf ? ((const float*)bp)[c] : bf2f(((const ushort*)bp)[c]);
    btc = a + b + 1e-6f;
  }

  for (int row0 = blockIdx.x * 64; row0 < M; row0 += gridDim.x * 64) {
    for (int u = tid; u < 1024; u += 512) {
      int row = u >> 4, kc = u & 15;
      int grow = row0 + row;
      uint4 hi = make_uint4(0, 0, 0, 0), lo = make_uint4(0, 0, 0, 0);
      if (isf) {
        if (grow < M) {
          const float4* Xf = (const float4*)X;
          float4 v0 = Xf[(size_t)grow * 32 + kc * 2];
          float4 v1 = Xf[(size_t)grow * 32 + kc * 2 + 1];
          float v[8] = {v0.x, v0.y, v0.z, v0.w, v1.x, v1.y, v1.z, v1.w};
          uint hw[4], lw[4];
#pragma unroll
          for (int j = 0; j < 4; ++j) {
            ushort h0 = f2bf(v[2 * j]), h1 = f2bf(v[2 * j + 1]);
            ushort l0 = f2bf(v[2 * j] - bf2f(h0));
            ushort l1 = f2bf(v[2 * j + 1] - bf2f(h1));
            hw[j] = (uint)h0 | ((uint)h1 << 16);
            lw[j] = (uint)l0 | ((uint)l1 << 16);
          }
          hi = make_uint4(hw[0], hw[1], hw[2], hw[3]);
          lo = make_uint4(lw[0], lw[1], lw[2], lw[3]);
        }
      } else {
        if (grow < M) hi = ((const uint4*)X)[(size_t)grow * 16 + kc];
      }
      int ln = (kc & 3) * 16 + (row & 15);
      int g = row >> 4, kt = kc >> 2;
      aF[g][kt][0][ln] = hi;
      if (isf) aF[g][kt][1][ln] = lo;
    }
    __syncthreads();

#pragma unroll
    for (int g = 0; g < 4; ++g) {
      f32x4 accG = {0.f, 0.f, 0.f, 0.f};
      f32x4 accP = {0.f, 0.f, 0.f, 0.f};
      uint4 aH[4];
#pragma unroll
      for (int kt = 0; kt < 4; ++kt) aH[kt] = aF[g][kt][0][lane];
#pragma unroll
      for (int kt = 0; kt < 4; ++kt) {
        short8 a = __builtin_bit_cast(short8, aH[kt]);
        accG = __builtin_amdgcn_mfma_f32_16x16x32_bf16(a, bG[kt], accG, 0, 0, 0);
        accP = __builtin_amdgcn_mfma_f32_16x16x32_bf16(a, bP[kt], accP, 0, 0, 0);
      }
      if (isf) {
        uint4 aL[4];
#pragma unroll
        for (int kt = 0; kt < 4; ++kt) aL[kt] = aF[g][kt][1][lane];
#pragma unroll
        for (int kt = 0; kt < 4; ++kt) {
          short8 a = __builtin_bit_cast(short8, aL[kt]);
          accG = __builtin_amdgcn_mfma_f32_16x16x32_bf16(a, bG[kt], accG, 0, 0, 0);
          accP = __builtin_amdgcn_mfma_f32_16x16x32_bf16(a, bP[kt], accP, 0, 0, 0);
        }
      }
      int rl0 = g * 16 + kg * 4;
#pragma unroll
      for (int r = 0; r < 4; ++r) {
        int row = row0 + rl0 + r;
        if (row < M) {
          float dn = dinv[row];
          float gv = accG[r], pv = accP[r];
          xwl[rl0 + r][c] = f2bf(gv * dn);
          float ov = fmaf(gv, dn * dn, pv + btc);
          if (isf)
            ((float*)outx3)[(size_t)row * D + c] = ov;
          else
            ((ushort*)outx3)[(size_t)row * D + c] = f2bf(ov);
        }
      }
    }
    __syncthreads();

    int valid = min(64, M - row0);
    const uint4* src = (const uint4*)xwl;
    uint4* dst = (uint4*)xw2 + (size_t)row0 * 16;
    for (int u = tid; u < valid * 16; u += 512) dst[u] = src[u];
  }
}

// ---------------------------------------------------------------------------
// MFMA drug GEMM: yd2[M][64] bf16 pairs = x_drug @ W_td + b_td
// ---------------------------------------------------------------------------
__global__ __launch_bounds__(512) void gemm_drug_mfma(
    const void* __restrict__ X, const void* __restrict__ W,
    const void* __restrict__ bias, uint* __restrict__ Y2,
    const int* __restrict__ flag, int M) {
  __shared__ uint4 aF[4][4][2][64];  // 32 KB
  __shared__ ushort yl[64][128];     // 16 KB
  const int isf = *flag;
  const int tid = threadIdx.x;
  const int wv = tid >> 6, lane = tid & 63;
  const int cl = lane & 15, kg = lane >> 4;
  const int c = wv * 16 + cl;

  short8 bT[4];
#pragma unroll
  for (int kt = 0; kt < 4; ++kt) {
    int k0 = kt * 32 + 8 * kg;
    short8 ft;
    if (isf) {
      const float* Wf = (const float*)W;
#pragma unroll
      for (int j = 0; j < 8; ++j) ft[j] = (short)f2bf(Wf[(k0 + j) * D + c]);
    } else {
      const ushort* Wh = (const ushort*)W;
#pragma unroll
      for (int j = 0; j < 8; ++j) ft[j] = (short)Wh[(k0 + j) * D + c];
    }
    bT[kt] = ft;
  }
  float btc = isf ? ((const float*)bias)[c] : bf2f(((const ushort*)bias)[c]);

  for (int row0 = blockIdx.x * 64; row0 < M; row0 += gridDim.x * 64) {
    for (int u = tid; u < 1024; u += 512) {
      int row = u >> 4, kc = u & 15;
      int grow = row0 + row;
      uint4 hi = make_uint4(0, 0, 0, 0), lo = make_uint4(0, 0, 0, 0);
      if (isf) {
        if (grow < M) {
          const float4* Xf = (const float4*)X;
          float4 v0 = Xf[(size_t)grow * 32 + kc * 2];
          float4 v1 = Xf[(size_t)grow * 32 + kc * 2 + 1];
          float v[8] = {v0.x, v0.y, v0.z, v0.w, v1.x, v1.y, v1.z, v1.w};
          uint hw[4], lw[4];
#pragma unroll
          for (int j = 0; j < 4; ++j) {
            ushort h0 = f2bf(v[2 * j]), h1 = f2bf(v[2 * j + 1]);
            ushort l0 = f2bf(v[2 * j] - bf2f(h0));
            ushort l1 = f2bf(v[2 * j + 1] - bf2f(h1));
            hw[j] = (uint)h0 | ((uint)h1 << 16);
            lw[j] = (uint)l0 | ((uint)l1 << 16);
          }
          hi = make_uint4(hw[0], hw[1], hw[2], hw[3]);
          lo = make_uint4(lw[0], lw[1], lw[2], lw[3]);
        }
      } else {
        if (grow < M) hi = ((const uint4*)X)[(size_t)grow * 16 + kc];
      }
      int ln = (kc & 3) * 16 + (row & 15);
      int g = row >> 4, kt = kc >> 2;
      aF[g][kt][0][ln] = hi;
      if (isf) aF[g][kt][1][ln] = lo;
    }
    __syncthreads();

#pragma unroll
    for (int g = 0; g < 4; ++g) {
      f32x4 acc = {0.f, 0.f, 0.f, 0.f};
      uint4 aH[4];
#pragma unroll
      for (int kt = 0; kt < 4; ++kt) aH[kt] = aF[g][kt][0][lane];
#pragma unroll
      for (int kt = 0; kt < 4; ++kt) {
        short8 a = __builtin_bit_cast(short8, aH[kt]);
        acc = __builtin_amdgcn_mfma_f32_16x16x32_bf16(a, bT[kt], acc, 0, 0, 0);
      }
      if (isf) {
        uint4 aL[4];
#pragma unroll
        for (int kt = 0; kt < 4; ++kt) aL[kt] = aF[g][kt][1][lane];
#pragma unroll
        for (int kt = 0; kt < 4; ++kt) {
          short8 a = __builtin_bit_cast(short8, aL[kt]);
          acc = __builtin_amdgcn_mfma_f32_16x16x32_bf16(a, bT[kt], acc, 0, 0, 0);
        }
      }
      int rl0 = g * 16 + kg * 4;
#pragma unroll
      for (int r = 0; r < 4; ++r) {
        int row = row0 + rl0 + r;
        if (row < M) yl[rl0 + r][c] = f2bf(acc[r] + btc);
      }
    }
    __syncthreads();

    int valid = min(64, M - row0);
    const uint4* src = (const uint4*)yl;
    uint4* dst = (uint4*)Y2 + (size_t)row0 * 16;
    for (int u = tid; u < valid * 16; u += 512) dst[u] = src[u];
  }
}

// ---------------------------------------------------------------------------
// Gather + LayerNorm. One wave per node; four 16-lane groups each gather one
// edge row as 16B dwordx4 (4 edges per VMEM instruction slot).
// ---------------------------------------------------------------------------
__global__ __launch_bounds__(256) void gather_ln_kernel(
    const uint* __restrict__ xw2, const uint* __restrict__ yd2,
    const float* __restrict__ dinv, const float* __restrict__ invcnt,
    const int* __restrict__ offsets, const int* __restrict__ deg,
    const uint* __restrict__ csr, void* __restrict__ out,
    const int* __restrict__ flag, int n_prot) {
  const int isf = *flag;
  const int node = (blockIdx.x * 256 + threadIdx.x) >> 6;
  const int lane = threadIdx.x & 63;
  const int grp = lane >> 4;  // 0..3 : edge sub-group
  const int li = lane & 15;   // cols [li*8, li*8+8)  (uint4 index li)
  if (node >= n_prot) return;
  const int s0 = offsets[node];
  const int s1 = offsets[node + 1];
  const int sm = s0 + deg[node];
  const float dn = dinv[node], ic = invcnt[node];

  float aP[8] = {0.f, 0.f, 0.f, 0.f, 0.f, 0.f, 0.f, 0.f};
  float aD[8] = {0.f, 0.f, 0.f, 0.f, 0.f, 0.f, 0.f, 0.f};

  const uint4* X4 = (const uint4*)xw2;
  const uint4* Y4 = (const uint4*)yd2;

#pragma unroll
  for (int part = 0; part < 2; ++part) {
    const uint4* T = part ? Y4 : X4;
    float* acc = part ? aD : aP;
    int a = part ? sm : s0;
    int b = part ? s1 : sm;
    for (int base = a; base < b;) {
      int m = min(64, b - base);
      uint ent = (lane < m) ? csr[base + lane] : 0u;
      int nb4 = m >> 2;
      int t = 0;
      for (; t + 4 <= nb4; t += 4) {  // 16 edges, 4 loads in flight per lane
        uint e0 = __shfl(ent, (t + 0) * 4 + grp);
        uint e1 = __shfl(ent, (t + 1) * 4 + grp);
        uint e2 = __shfl(ent, (t + 2) * 4 + grp);
        uint e3 = __shfl(ent, (t + 3) * 4 + grp);
        uint4 w0 = T[(size_t)e0 * 16 + li];
        uint4 w1 = T[(size_t)e1 * 16 + li];
        uint4 w2 = T[(size_t)e2 * 16 + li];
        uint4 w3 = T[(size_t)e3 * 16 + li];
        acc8(acc, w0);
        acc8(acc, w1);
        acc8(acc, w2);
        acc8(acc, w3);
      }
      for (; t < nb4; ++t) {
        uint e = __shfl(ent, t * 4 + grp);
        uint4 w = T[(size_t)e * 16 + li];
        acc8(acc, w);
      }
      int rem = m & 3;
      if (rem) {
        uint e = __shfl(ent, nb4 * 4 + grp);
        if (grp < rem) {
          uint4 w = T[(size_t)e * 16 + li];
          acc8(acc, w);
        }
      }
      base += m;
    }
  }

  // combine lists, reduce across the 4 groups (lanes ^16, ^32)
  float v[8];
#pragma unroll
  for (int i = 0; i < 8; ++i) v[i] = fmaf(dn, aP[i], ic * aD[i]);
#pragma unroll
  for (int i = 0; i < 8; ++i) {
    v[i] += __shfl_xor(v[i], 16);
    v[i] += __shfl_xor(v[i], 32);
  }

  // add x3' (read from out, in output dtype)
  if (isf) {
    const float4* xr = (const float4*)out + (size_t)node * 32 + li * 2;
    float4 x0 = xr[0], x1 = xr[1];
    v[0] += x0.x; v[1] += x0.y; v[2] += x0.z; v[3] += x0.w;
    v[4] += x1.x; v[5] += x1.y; v[6] += x1.z; v[7] += x1.w;
  } else {
    uint4 xr = ((const uint4*)out)[(size_t)node * 16 + li];
    float2 t0 = bf16x2(xr.x), t1 = bf16x2(xr.y);
    float2 t2 = bf16x2(xr.z), t3 = bf16x2(xr.w);
    v[0] += t0.x; v[1] += t0.y; v[2] += t1.x; v[3] += t1.y;
    v[4] += t2.x; v[5] += t2.y; v[6] += t3.x; v[7] += t3.y;
  }

  // LayerNorm over 128 cols (each li owns 8; reduce over 16 lanes)
  float s = 0.f, ss = 0.f;
#pragma unroll
  for (int i = 0; i < 8; ++i) {
    s += v[i];
    ss = fmaf(v[i], v[i], ss);
  }
#pragma unroll
  for (int off = 1; off < 16; off <<= 1) {
    s += __shfl_xor(s, off);
    ss += __shfl_xor(ss, off);
  }
  float mu = s * (1.0f / 128.0f);
  float var = ss * (1.0f / 128.0f) - mu * mu;
  float rs = rsqrtf(var + 1e-5f);
#pragma unroll
  for (int i = 0; i < 8; ++i) v[i] = (v[i] - mu) * rs;

  if (isf) {
    if (grp < 2) {  // 32 lanes cover the 512B row
      float4 o = (grp == 0) ? make_float4(v[0], v[1], v[2], v[3])
                            : make_float4(v[4], v[5], v[6], v[7]);
      ((float4*)out)[(size_t)node * 32 + li * 2 + grp] = o;
    }
  } else {
    if (grp == 0) {
      uint4 o;
      o.x = pack_bf16x2(v[0], v[1]);
      o.y = pack_bf16x2(v[2], v[3]);
      o.z = pack_bf16x2(v[4], v[5]);
      o.w = pack_bf16x2(v[6], v[7]);
      ((uint4*)out)[(size_t)node * 16 + li] = o;
    }
  }
}

// ---------------------------------------------------------------------------
extern "C" void kernel_launch(void* const* d_in, const int* in_sizes, int n_in,
                              void* d_out, int out_size, void* d_ws,
                              size_t ws_size, hipStream_t stream) {
  const void* x_prot = d_in[0];
  const void* x_drug = d_in[1];
  const void* W_gcn = d_in[2];
  const void* b_gcn = d_in[3];
  const void* W_td = d_in[4];
  const void* b_td = d_in[5];
  const void* W_pr = d_in[6];
  const void* b_pr = d_in[7];
  const int* ppi = (const int*)d_in[8];
  const int* dti_drug = (const int*)d_in[9];
  const int* dti_prot = (const int*)d_in[10];

  int n_prot = in_sizes[0] / D;
  int n_drug = in_sizes[1] / D;
  int e_ppi = in_sizes[8] / 2;
  int e_dti = in_sizes[9];
  int e_tot = e_ppi + e_dti;
  int nb = (n_prot + 255) / 256;
  int nbk = (n_prot + NPBK - 1) / NPBK;  // coarse buckets (== nb here)

  char* ws = (char*)d_ws;
  size_t off = 0;
  auto alloc = [&](size_t bytes) {
    void* p = ws + off;
    off = (off + bytes + 255) & ~(size_t)255;
    return p;
  };
  int* flag = (int*)alloc(256);
  uint* xw2 = (uint*)alloc((size_t)n_prot * 64 * 4);  // 25.6 MB (pre-scaled)
  uint* yd2 = (uint*)alloc((size_t)n_drug * 64 * 4);  //  5.1 MB
  int* deg = (int*)alloc((size_t)n_prot * 4);
  int* cnt = (int*)alloc((size_t)n_prot * 4);
  float* dinv = (float*)alloc((size_t)n_prot * 4);
  float* invcnt = (float*)alloc((size_t)n_prot * 4);
  int* offsets = (int*)alloc((size_t)(n_prot + 1) * 4);
  int* fposp = (int*)alloc((size_t)n_prot * 4);
  int* fposd = (int*)alloc((size_t)n_prot * 4);
  int* bsum = (int*)alloc((size_t)nb * 4);
  int* gbh = (int*)alloc((size_t)NBMAX * 4);
  int* bbase = (int*)alloc((size_t)(NBMAX + 1) * 4);
  int* bcur = (int*)alloc((size_t)NBMAX * 4);
  uint* csr = (uint*)alloc((size_t)e_tot * 4);  // 9.6 MB

  if (off > ws_size) return;  // insufficient workspace: bail cleanly

  // Partitioned-edge scratch aliases xw2: place_count finishes before
  // gemm_prot_mfma writes xw2 (same stream), and e_tot*4 <= n_prot*256 here.
  uint* P = xw2;
  bool fast_fill = (n_prot <= (1 << 17)) && (n_drug <= (1 << 17)) &&
                   (nbk <= NBMAX) && ((size_t)e_tot * 4 <= (size_t)n_prot * 256);

  detect_kernel<<<1, 256, 0, stream>>>((const uint*)x_prot, 4096, flag);

  if (fast_fill) {
    hipMemsetAsync(gbh, 0, (size_t)NBMAX * 4, stream);
    bucket_hist_kernel<<<(e_tot + 8191) / 8192, 256, 0, stream>>>(
        ppi + e_ppi, dti_prot, gbh, e_ppi, e_dti, n_prot, nbk);
    bucket_scan_kernel<<<1, NBMAX, 0, stream>>>(gbh, bbase, bcur, nbk);
    partition_kernel<<<(e_tot + TILE_A - 1) / TILE_A, 256, 0, stream>>>(
        ppi, ppi + e_ppi, dti_drug, dti_prot, bcur, P, e_ppi, e_dti, n_prot,
        nbk);
    place_count_kernel<<<nbk, 1024, 0, stream>>>(
        P, bbase, csr, deg, dinv, invcnt, offsets, n_prot, nbk);
  } else {
    hipMemsetAsync(deg, 0, (size_t)n_prot * 4, stream);
    hipMemsetAsync(cnt, 0, (size_t)n_prot * 4, stream);
    hipMemsetAsync(fposp, 0, (size_t)n_prot * 4, stream);
    hipMemsetAsync(fposd, 0, (size_t)n_prot * 4, stream);
    count_kernel<<<(e_tot + 255) / 256, 256, 0, stream>>>(
        ppi + e_ppi, dti_prot, deg, cnt, e_ppi, e_dti, n_prot);
    block_sum_kernel<<<nb, 256, 0, stream>>>(deg, cnt, n_prot, dinv, invcnt,
                                             bsum);
    scan_bsums_kernel<<<1, 1024, 0, stream>>>(bsum, nb);
    scan_final_kernel<<<nb, 256, 0, stream>>>(deg, cnt, bsum, offsets, n_prot);
    fill_kernel<<<(e_tot + 255) / 256, 256, 0, stream>>>(
        ppi, ppi + e_ppi, dti_drug, dti_prot, offsets, deg, fposp, fposd, csr,
        e_ppi, e_dti, n_prot);
  }

  int nbat_p = (n_prot + 63) / 64;
  int grid_p = nbat_p < 512 ? nbat_p : 512;
  gemm_prot_mfma<<<grid_p, 512, 0, stream>>>(x_prot, W_gcn, W_pr, b_gcn, b_pr,
                                             dinv, xw2, d_out, flag, n_prot);
  int nbat_d = (n_drug + 63) / 64;
  int grid_d = nbat_d < 512 ? nbat_d : 512;
  gemm_drug_mfma<<<grid_d, 512, 0, stream>>>(x_drug, W_td, b_td, yd2, flag,
                                             n_drug);

  gather_ln_kernel<<<(n_prot + 3) / 4, 256, 0, stream>>>(
      xw2, yd2, dinv, invcnt, offsets, deg, csr, d_out, flag, n_prot);
}

// Round 7
// 318.644 us; speedup vs baseline: 1.3029x; 1.0463x over previous
//
#include <hip/hip_runtime.h>
#include <hip/hip_bf16.h>

#define D 128
#define NPBK 256     // nodes per coarse bucket (partition/placement)
#define NBMAX 512    // max coarse buckets supported by LDS arrays
#define TILE_A 4096  // edges per partition block (256 thr x 16)
#define SEGMAX 8192  // max bucket segment for LDS-staged csr writeout

typedef unsigned int uint;
typedef unsigned short ushort;
typedef __attribute__((ext_vector_type(8))) short short8;
typedef __attribute__((ext_vector_type(4))) float f32x4;

// unpack a bf16x2 (as uint) into two floats: x = low half, y = high half
static __device__ __forceinline__ float2 bf16x2(uint u) {
  float2 r;
  r.x = __uint_as_float(u << 16);
  r.y = __uint_as_float(u & 0xffff0000u);
  return r;
}

static __device__ __forceinline__ uint pack_bf16x2(float a, float b) {
  __hip_bfloat162 o;
  o.x = __float2bfloat16(a);
  o.y = __float2bfloat16(b);
  return *reinterpret_cast<uint*>(&o);
}

static __device__ __forceinline__ ushort f2bf(float f) {
  __hip_bfloat16 h = __float2bfloat16(f);
  return *reinterpret_cast<ushort*>(&h);
}
static __device__ __forceinline__ float bf2f(ushort u) {
  return __uint_as_float(((uint)u) << 16);
}

// accumulate 8 bf16 values (packed in a uint4) into acc[0..7]
static __device__ __forceinline__ void acc8(float* acc, uint4 v) {
  float2 t0 = bf16x2(v.x), t1 = bf16x2(v.y);
  float2 t2 = bf16x2(v.z), t3 = bf16x2(v.w);
  acc[0] += t0.x; acc[1] += t0.y;
  acc[2] += t1.x; acc[3] += t1.y;
  acc[4] += t2.x; acc[5] += t2.y;
  acc[6] += t3.x; acc[7] += t3.y;
}

// ---------------------------------------------------------------------------
// Detect input dtype (bf16 vs fp32 storage). flag=1 means fp32.
// ---------------------------------------------------------------------------
__global__ void detect_kernel(const uint* __restrict__ x, int n_words,
                              int* __restrict__ flag) {
  __shared__ float smax[256];
  float m = 0.f;
  for (int i = threadIdx.x; i < n_words; i += 256) {
    float2 v = bf16x2(x[i]);
    float a = fabsf(v.x), b = fabsf(v.y);
    if (!(a <= 1e30f)) a = 1e30f;
    if (!(b <= 1e30f)) b = 1e30f;
    m = fmaxf(m, fmaxf(a, b));
  }
  smax[threadIdx.x] = m;
  __syncthreads();
  for (int s = 128; s > 0; s >>= 1) {
    if (threadIdx.x < s)
      smax[threadIdx.x] = fmaxf(smax[threadIdx.x], smax[threadIdx.x + s]);
    __syncthreads();
  }
  if (threadIdx.x == 0) *flag = (smax[0] > 1e6f) ? 1 : 0;
}

// ---------------------------------------------------------------------------
// FAST PATH pass 0: coarse bucket histogram (LDS) -> global bucket totals.
// ---------------------------------------------------------------------------
__global__ __launch_bounds__(256) void bucket_hist_kernel(
    const int* __restrict__ ppi_col, const int* __restrict__ dti_prot,
    int* __restrict__ gbh, int e_ppi, int e_dti, int n_prot, int nbk) {
  __shared__ int hist[NBMAX];
  const int tid = threadIdx.x;
  for (int b = tid; b < nbk; b += 256) hist[b] = 0;
  __syncthreads();
  const int e_tot = e_ppi + e_dti;
  const int base = blockIdx.x * 8192;
#pragma unroll 4
  for (int j = 0; j < 32; ++j) {
    int i = base + j * 256 + tid;
    if (i < e_tot) {
      int dst = (i < e_ppi) ? ppi_col[i] : dti_prot[i - e_ppi];
      if ((unsigned)dst < (unsigned)n_prot) atomicAdd(&hist[dst >> 8], 1);
    }
  }
  __syncthreads();
  for (int b = tid; b < nbk; b += 256) {
    int h = hist[b];
    if (h) atomicAdd(&gbh[b], h);
  }
}

// single block (NBMAX threads): exclusive scan of bucket totals -> bbase,
// and init allocation cursors bcur.
__global__ __launch_bounds__(NBMAX) void bucket_scan_kernel(
    const int* __restrict__ gbh, int* __restrict__ bbase,
    int* __restrict__ bcur, int nbk) {
  __shared__ int sh[NBMAX];
  const int tid = threadIdx.x;
  int v = (tid < nbk) ? gbh[tid] : 0;
  sh[tid] = v;
  __syncthreads();
  for (int ofs = 1; ofs < NBMAX; ofs <<= 1) {
    int t = (tid >= ofs) ? sh[tid - ofs] : 0;
    __syncthreads();
    sh[tid] += t;
    __syncthreads();
  }
  if (tid < nbk) {
    int e = sh[tid] - v;  // exclusive
    bbase[tid] = e;
    bcur[tid] = e;
    if (tid == nbk - 1) bbase[nbk] = sh[tid];
  }
}

// ---------------------------------------------------------------------------
// FAST PATH pass A: partition edges into coarse dst-buckets (256 nodes each).
// Packed entry: src(17b) | type(1b)<<17 | (dst&255)<<18 -> one uint.
// v2: in-block LDS counting sort, then COALESCED copy-out (consecutive LDS
// slots map to consecutive global addresses within each bucket run).
// ---------------------------------------------------------------------------
__global__ __launch_bounds__(256) void partition_kernel(
    const int* __restrict__ ppi_row, const int* __restrict__ ppi_col,
    const int* __restrict__ dti_drug, const int* __restrict__ dti_prot,
    int* __restrict__ bcur, uint* __restrict__ P, int e_ppi, int e_dti,
    int n_prot, int nb) {
  __shared__ int hist[NBMAX];
  __shared__ int sh[NBMAX];
  __shared__ int lbase[NBMAX];
  __shared__ int gbase[NBMAX];
  __shared__ int cur[NBMAX];
  __shared__ uint entL[TILE_A];    // 16 KB
  __shared__ ushort bktL[TILE_A];  // 8 KB
  const int tid = threadIdx.x;
  const int base = blockIdx.x * TILE_A;
  const int e_tot = e_ppi + e_dti;

  for (int b = tid; b < nb; b += 256) hist[b] = 0;
  __syncthreads();

  uint sv[16];
  int dv[16];
#pragma unroll
  for (int j = 0; j < 16; ++j) {
    int i = base + j * 256 + tid;
    int d = -1;
    uint s = 0;
    if (i < e_tot) {
      int src, dst, type;
      if (i < e_ppi) {
        src = ppi_row[i];
        dst = ppi_col[i];
        type = 0;
      } else {
        int k = i - e_ppi;
        src = dti_drug[k];
        dst = dti_prot[k];
        type = 1;
      }
      if ((unsigned)dst < (unsigned)n_prot) {
        d = dst;
        s = (uint)src | ((uint)type << 17);
        atomicAdd(&hist[dst >> 8], 1);
      }
    }
    sv[j] = s;
    dv[j] = d;
  }
  __syncthreads();

  // inclusive scan of hist over NBMAX padded slots (256 threads x 2 slots)
  {
    int t2 = tid + 256;
    sh[tid] = (tid < nb) ? hist[tid] : 0;
    sh[t2] = (t2 < nb) ? hist[t2] : 0;
    __syncthreads();
    for (int ofs = 1; ofs < NBMAX; ofs <<= 1) {
      int a0 = (tid >= ofs) ? sh[tid - ofs] : 0;
      int a1 = (t2 >= ofs) ? sh[t2 - ofs] : 0;
      __syncthreads();
      sh[tid] += a0;
      sh[t2] += a1;
      __syncthreads();
    }
  }

  for (int b = tid; b < nb; b += 256) {
    int h = hist[b];
    int lb = sh[b] - h;
    lbase[b] = lb;
    cur[b] = lb;
    gbase[b] = h ? atomicAdd(&bcur[b], h) : 0;
  }
  __syncthreads();

  // scatter into LDS staging, sorted by bucket
#pragma unroll
  for (int j = 0; j < 16; ++j) {
    if (dv[j] >= 0) {
      int b = dv[j] >> 8;
      int r = atomicAdd(&cur[b], 1);
      entL[r] = sv[j] | ((uint)(dv[j] & (NPBK - 1)) << 18);
      bktL[r] = (ushort)b;
    }
  }
  __syncthreads();

  // coalesced copy-out: run of bucket b occupies consecutive u and
  // consecutive global addresses gbase[b] + (u - lbase[b]).
  const int tot = sh[NBMAX - 1];
  for (int u = tid; u < tot; u += 256) {
    int b = bktL[u];
    P[gbase[b] + (u - lbase[b])] = entL[u];
  }
}

// ---------------------------------------------------------------------------
// FAST PATH pass B (fused): one block per bucket.
//  1) stream P segment: per-node deg/cnt histogram in LDS
//  2) LDS scan -> per-node offsets; write deg/dinv/invcnt/offsets sequentially
//  3) re-read P (L2-hot), scatter into LDS srt[], stream csr out COALESCED
// ---------------------------------------------------------------------------
__global__ __launch_bounds__(1024) void place_count_kernel(
    const uint* __restrict__ P, const int* __restrict__ bbase,
    uint* __restrict__ csr, int* __restrict__ deg, float* __restrict__ dinv,
    float* __restrict__ invcnt, int* __restrict__ offsets, int n_prot,
    int nbk) {
  __shared__ int degL[NPBK], cntL[NPBK];
  __shared__ int cp[NPBK], cd[NPBK];
  __shared__ int sc[NPBK];
  __shared__ uint srt[SEGMAX];  // 32 KB
  const int tid = threadIdx.x;
  const int b = blockIdx.x;
  const int node0 = b * NPBK;
  const int nn = min(NPBK, n_prot - node0);
  const int start = bbase[b], end = bbase[b + 1];
  const int nseg = end - start;

  if (tid < NPBK) {
    degL[tid] = 0;
    cntL[tid] = 0;
  }
  __syncthreads();

  for (int i = start + tid; i < end; i += 1024) {
    uint p = P[i];
    int nl = (int)(p >> 18);
    if ((p >> 17) & 1u)
      atomicAdd(&cntL[nl], 1);
    else
      atomicAdd(&degL[nl], 1);
  }
  __syncthreads();

  // inclusive scan over per-node totals (256 entries), local 0-based
  int v = 0;
  if (tid < NPBK) {
    v = (tid < nn) ? (degL[tid] + cntL[tid]) : 0;
    sc[tid] = v;
  }
  __syncthreads();
  for (int ofs = 1; ofs < NPBK; ofs <<= 1) {
    int t = 0;
    if (tid < NPBK && tid >= ofs) t = sc[tid - ofs];
    __syncthreads();
    if (tid < NPBK) sc[tid] += t;
    __syncthreads();
  }
  if (tid < nn) {
    int d = degL[tid], c = cntL[tid];
    int lexcl = sc[tid] - v;  // local position within segment
    int node = node0 + tid;
    offsets[node] = start + lexcl;
    deg[node] = d;
    dinv[node] = rsqrtf((float)(d + 1));  // +1 self-loop
    invcnt[node] = 1.0f / fmaxf((float)c, 1.0f);
    cp[tid] = lexcl;
    cd[tid] = lexcl + d;
  }
  if (b == nbk - 1 && tid == 0) offsets[n_prot] = end;
  __syncthreads();

  if (nseg <= SEGMAX) {
    // sort into LDS, then coalesced writeout
    for (int i = start + tid; i < end; i += 1024) {
      uint p = P[i];  // L2-hot re-read
      int nl = (int)(p >> 18);
      int pos =
          ((p >> 17) & 1u) ? atomicAdd(&cd[nl], 1) : atomicAdd(&cp[nl], 1);
      srt[pos] = p & 0x1ffffu;
    }
    __syncthreads();
    for (int u = tid; u < nseg; u += 1024) csr[start + u] = srt[u];
  } else {
    // oversized segment: direct scattered writes (window still L2-resident)
    for (int i = start + tid; i < end; i += 1024) {
      uint p = P[i];
      int nl = (int)(p >> 18);
      int pos =
          ((p >> 17) & 1u) ? atomicAdd(&cd[nl], 1) : atomicAdd(&cp[nl], 1);
      csr[start + pos] = p & 0x1ffffu;
    }
  }
}

// ---------------------------------------------------------------------------
// FALLBACK path kernels (used only when packing guards fail).
// ---------------------------------------------------------------------------
__global__ void count_kernel(const int* __restrict__ ppi_col,
                             const int* __restrict__ dti_prot,
                             int* __restrict__ deg, int* __restrict__ cnt,
                             int e_ppi, int e_dti, int n_prot) {
  int i = blockIdx.x * blockDim.x + threadIdx.x;
  if (i < e_ppi) {
    int c = ppi_col[i];
    if ((unsigned)c < (unsigned)n_prot) atomicAdd(&deg[c], 1);
  } else if (i < e_ppi + e_dti) {
    int c = dti_prot[i - e_ppi];
    if ((unsigned)c < (unsigned)n_prot) atomicAdd(&cnt[c], 1);
  }
}

__global__ void block_sum_kernel(const int* __restrict__ deg,
                                 const int* __restrict__ cnt, int n,
                                 float* __restrict__ dinv,
                                 float* __restrict__ invcnt,
                                 int* __restrict__ bsum) {
  __shared__ int sh[256];
  int i = blockIdx.x * 256 + threadIdx.x;
  int t = 0;
  if (i < n) {
    int d = deg[i], c = cnt[i];
    dinv[i] = rsqrtf((float)(d + 1));  // +1 self-loop
    invcnt[i] = 1.0f / fmaxf((float)c, 1.0f);
    t = d + c;
  }
  sh[threadIdx.x] = t;
  __syncthreads();
  for (int s = 128; s > 0; s >>= 1) {
    if (threadIdx.x < s) sh[threadIdx.x] += sh[threadIdx.x + s];
    __syncthreads();
  }
  if (threadIdx.x == 0) bsum[blockIdx.x] = sh[0];
}

__global__ void scan_bsums_kernel(int* __restrict__ bsum, int nb) {
  __shared__ int sh[1024];
  __shared__ int carry;
  int tid = threadIdx.x;
  if (tid == 0) carry = 0;
  __syncthreads();
  for (int base = 0; base < nb; base += 1024) {
    int i = base + tid;
    int v = (i < nb) ? bsum[i] : 0;
    sh[tid] = v;
    __syncthreads();
    for (int ofs = 1; ofs < 1024; ofs <<= 1) {
      int t = (tid >= ofs) ? sh[tid - ofs] : 0;
      __syncthreads();
      sh[tid] += t;
      __syncthreads();
    }
    if (i < nb) bsum[i] = carry + sh[tid] - v;  // exclusive
    int total = sh[1023];
    __syncthreads();
    if (tid == 0) carry += total;
    __syncthreads();
  }
}

__global__ void scan_final_kernel(const int* __restrict__ deg,
                                  const int* __restrict__ cnt,
                                  const int* __restrict__ bbase,
                                  int* __restrict__ offsets, int n) {
  __shared__ int sh[256];
  int tid = threadIdx.x;
  int i = blockIdx.x * 256 + tid;
  int v = (i < n) ? deg[i] + cnt[i] : 0;
  sh[tid] = v;
  __syncthreads();
  for (int ofs = 1; ofs < 256; ofs <<= 1) {
    int t = (tid >= ofs) ? sh[tid - ofs] : 0;
    __syncthreads();
    sh[tid] += t;
    __syncthreads();
  }
  if (i < n) {
    int excl = bbase[blockIdx.x] + sh[tid] - v;
    offsets[i] = excl;
    if (i == n - 1) offsets[n] = excl + v;
  }
}

__global__ void fill_kernel(const int* __restrict__ ppi_row,
                            const int* __restrict__ ppi_col,
                            const int* __restrict__ dti_drug,
                            const int* __restrict__ dti_prot,
                            const int* __restrict__ offsets,
                            const int* __restrict__ deg,
                            int* __restrict__ fposp, int* __restrict__ fposd,
                            uint* __restrict__ csr, int e_ppi, int e_dti,
                            int n_prot) {
  int i = blockIdx.x * blockDim.x + threadIdx.x;
  if (i < e_ppi) {
    int dst = ppi_col[i];
    if ((unsigned)dst >= (unsigned)n_prot) return;
    int pos = offsets[dst] + atomicAdd(&fposp[dst], 1);
    csr[pos] = (uint)ppi_row[i];
  } else if (i < e_ppi + e_dti) {
    int j = i - e_ppi;
    int dst = dti_prot[j];
    if ((unsigned)dst >= (unsigned)n_prot) return;
    int pos = offsets[dst] + deg[dst] + atomicAdd(&fposd[dst], 1);
    csr[pos] = (uint)dti_drug[j];
  }
}

// ---------------------------------------------------------------------------
// MFMA dual-output protein GEMM, 512 threads = 8 waves, 64 rows per iter.
//   g = x_prot[row] @ W_gcn  -> xw2[row] = bf16(g * dinv[row])
//   outx3[row] = x_prot[row] @ W_pr + (b_gcn+b_pr+1e-6) + dinv^2 * g
// fp32 x handled via hi/lo bf16 split (x = hi + lo).
// ---------------------------------------------------------------------------
__global__ __launch_bounds__(512) void gemm_prot_mfma(
    const void* __restrict__ X, const void* __restrict__ Wg,
    const void* __restrict__ Wp, const void* __restrict__ bg,
    const void* __restrict__ bp, const float* __restrict__ dinv,
    uint* __restrict__ xw2, void* __restrict__ outx3,
    const int* __restrict__ flag, int M) {
  __shared__ uint4 aF[4][4][2][64];  // [rowgrp][ktile][hi/lo][lane] : 32 KB
  __shared__ ushort xwl[64][128];    // transpose buffer for xw2 : 16 KB
  const int isf = *flag;
  const int tid = threadIdx.x;
  const int wv = tid >> 6, lane = tid & 63;
  const int cl = lane & 15, kg = lane >> 4;
  const int c = wv * 16 + cl;  // this wave's output column (0..127)

  short8 bG[4], bP[4];
#pragma unroll
  for (int kt = 0; kt < 4; ++kt) {
    int k0 = kt * 32 + 8 * kg;
    short8 fg, fp;
    if (isf) {
      const float* WgF = (const float*)Wg;
      const float* WpF = (const float*)Wp;
#pragma unroll
      for (int j = 0; j < 8; ++j) {
        fg[j] = (short)f2bf(WgF[(k0 + j) * D + c]);
        fp[j] = (short)f2bf(WpF[(k0 + j) * D + c]);
      }
    } else {
      const ushort* WgH = (const ushort*)Wg;
      const ushort* WpH = (const ushort*)Wp;
#pragma unroll
      for (int j = 0; j < 8; ++j) {
        fg[j] = (short)WgH[(k0 + j) * D + c];
        fp[j] = (short)WpH[(k0 + j) * D + c];
      }
    }
    bG[kt] = fg;
    bP[kt] = fp;
  }
  float btc;
  {
    float a = isf ? ((const float*)bg)[c] : bf2f(((const ushort*)bg)[c]);
    float b = isf ? ((const float*)bp)[c] : bf2f(((const ushort*)bp)[c]);
    btc = a + b + 1e-6f;
  }

  for (int row0 = blockIdx.x * 64; row0 < M; row0 += gridDim.x * 64) {
    for (int u = tid; u < 1024; u += 512) {
      int row = u >> 4, kc = u & 15;
      int grow = row0 + row;
      uint4 hi = make_uint4(0, 0, 0, 0), lo = make_uint4(0, 0, 0, 0);
      if (isf) {
        if (grow < M) {
          const float4* Xf = (const float4*)X;
          float4 v0 = Xf[(size_t)grow * 32 + kc * 2];
          float4 v1 = Xf[(size_t)grow * 32 + kc * 2 + 1];
          float v[8] = {v0.x, v0.y, v0.z, v0.w, v1.x, v1.y, v1.z, v1.w};
          uint hw[4], lw[4];
#pragma unroll
          for (int j = 0; j < 4; ++j) {
            ushort h0 = f2bf(v[2 * j]), h1 = f2bf(v[2 * j + 1]);
            ushort l0 = f2bf(v[2 * j] - bf2f(h0));
            ushort l1 = f2bf(v[2 * j + 1] - bf2f(h1));
            hw[j] = (uint)h0 | ((uint)h1 << 16);
            lw[j] = (uint)l0 | ((uint)l1 << 16);
          }
          hi = make_uint4(hw[0], hw[1], hw[2], hw[3]);
          lo = make_uint4(lw[0], lw[1], lw[2], lw[3]);
        }
      } else {
        if (grow < M) hi = ((const uint4*)X)[(size_t)grow * 16 + kc];
      }
      int ln = (kc & 3) * 16 + (row & 15);
      int g = row >> 4, kt = kc >> 2;
      aF[g][kt][0][ln] = hi;
      if (isf) aF[g][kt][1][ln] = lo;
    }
    __syncthreads();

#pragma unroll
    for (int g = 0; g < 4; ++g) {
      f32x4 accG = {0.f, 0.f, 0.f, 0.f};
      f32x4 accP = {0.f, 0.f, 0.f, 0.f};
      uint4 aH[4];
#pragma unroll
      for (int kt = 0; kt < 4; ++kt) aH[kt] = aF[g][kt][0][lane];
#pragma unroll
      for (int kt = 0; kt < 4; ++kt) {
        short8 a = __builtin_bit_cast(short8, aH[kt]);
        accG = __builtin_amdgcn_mfma_f32_16x16x32_bf16(a, bG[kt], accG, 0, 0, 0);
        accP = __builtin_amdgcn_mfma_f32_16x16x32_bf16(a, bP[kt], accP, 0, 0, 0);
      }
      if (isf) {
        uint4 aL[4];
#pragma unroll
        for (int kt = 0; kt < 4; ++kt) aL[kt] = aF[g][kt][1][lane];
#pragma unroll
        for (int kt = 0; kt < 4; ++kt) {
          short8 a = __builtin_bit_cast(short8, aL[kt]);
          accG = __builtin_amdgcn_mfma_f32_16x16x32_bf16(a, bG[kt], accG, 0, 0, 0);
          accP = __builtin_amdgcn_mfma_f32_16x16x32_bf16(a, bP[kt], accP, 0, 0, 0);
        }
      }
      int rl0 = g * 16 + kg * 4;
#pragma unroll
      for (int r = 0; r < 4; ++r) {
        int row = row0 + rl0 + r;
        if (row < M) {
          float dn = dinv[row];
          float gv = accG[r], pv = accP[r];
          xwl[rl0 + r][c] = f2bf(gv * dn);
          float ov = fmaf(gv, dn * dn, pv + btc);
          if (isf)
            ((float*)outx3)[(size_t)row * D + c] = ov;
          else
            ((ushort*)outx3)[(size_t)row * D + c] = f2bf(ov);
        }
      }
    }
    __syncthreads();

    int valid = min(64, M - row0);
    const uint4* src = (const uint4*)xwl;
    uint4* dst = (uint4*)xw2 + (size_t)row0 * 16;
    for (int u = tid; u < valid * 16; u += 512) dst[u] = src[u];
  }
}

// ---------------------------------------------------------------------------
// MFMA drug GEMM: yd2[M][64] bf16 pairs = x_drug @ W_td + b_td
// ---------------------------------------------------------------------------
__global__ __launch_bounds__(512) void gemm_drug_mfma(
    const void* __restrict__ X, const void* __restrict__ W,
    const void* __restrict__ bias, uint* __restrict__ Y2,
    const int* __restrict__ flag, int M) {
  __shared__ uint4 aF[4][4][2][64];  // 32 KB
  __shared__ ushort yl[64][128];     // 16 KB
  const int isf = *flag;
  const int tid = threadIdx.x;
  const int wv = tid >> 6, lane = tid & 63;
  const int cl = lane & 15, kg = lane >> 4;
  const int c = wv * 16 + cl;

  short8 bT[4];
#pragma unroll
  for (int kt = 0; kt < 4; ++kt) {
    int k0 = kt * 32 + 8 * kg;
    short8 ft;
    if (isf) {
      const float* Wf = (const float*)W;
#pragma unroll
      for (int j = 0; j < 8; ++j) ft[j] = (short)f2bf(Wf[(k0 + j) * D + c]);
    } else {
      const ushort* Wh = (const ushort*)W;
#pragma unroll
      for (int j = 0; j < 8; ++j) ft[j] = (short)Wh[(k0 + j) * D + c];
    }
    bT[kt] = ft;
  }
  float btc = isf ? ((const float*)bias)[c] : bf2f(((const ushort*)bias)[c]);

  for (int row0 = blockIdx.x * 64; row0 < M; row0 += gridDim.x * 64) {
    for (int u = tid; u < 1024; u += 512) {
      int row = u >> 4, kc = u & 15;
      int grow = row0 + row;
      uint4 hi = make_uint4(0, 0, 0, 0), lo = make_uint4(0, 0, 0, 0);
      if (isf) {
        if (grow < M) {
          const float4* Xf = (const float4*)X;
          float4 v0 = Xf[(size_t)grow * 32 + kc * 2];
          float4 v1 = Xf[(size_t)grow * 32 + kc * 2 + 1];
          float v[8] = {v0.x, v0.y, v0.z, v0.w, v1.x, v1.y, v1.z, v1.w};
          uint hw[4], lw[4];
#pragma unroll
          for (int j = 0; j < 4; ++j) {
            ushort h0 = f2bf(v[2 * j]), h1 = f2bf(v[2 * j + 1]);
            ushort l0 = f2bf(v[2 * j] - bf2f(h0));
            ushort l1 = f2bf(v[2 * j + 1] - bf2f(h1));
            hw[j] = (uint)h0 | ((uint)h1 << 16);
            lw[j] = (uint)l0 | ((uint)l1 << 16);
          }
          hi = make_uint4(hw[0], hw[1], hw[2], hw[3]);
          lo = make_uint4(lw[0], lw[1], lw[2], lw[3]);
        }
      } else {
        if (grow < M) hi = ((const uint4*)X)[(size_t)grow * 16 + kc];
      }
      int ln = (kc & 3) * 16 + (row & 15);
      int g = row >> 4, kt = kc >> 2;
      aF[g][kt][0][ln] = hi;
      if (isf) aF[g][kt][1][ln] = lo;
    }
    __syncthreads();

#pragma unroll
    for (int g = 0; g < 4; ++g) {
      f32x4 acc = {0.f, 0.f, 0.f, 0.f};
      uint4 aH[4];
#pragma unroll
      for (int kt = 0; kt < 4; ++kt) aH[kt] = aF[g][kt][0][lane];
#pragma unroll
      for (int kt = 0; kt < 4; ++kt) {
        short8 a = __builtin_bit_cast(short8, aH[kt]);
        acc = __builtin_amdgcn_mfma_f32_16x16x32_bf16(a, bT[kt], acc, 0, 0, 0);
      }
      if (isf) {
        uint4 aL[4];
#pragma unroll
        for (int kt = 0; kt < 4; ++kt) aL[kt] = aF[g][kt][1][lane];
#pragma unroll
        for (int kt = 0; kt < 4; ++kt) {
          short8 a = __builtin_bit_cast(short8, aL[kt]);
          acc = __builtin_amdgcn_mfma_f32_16x16x32_bf16(a, bT[kt], acc, 0, 0, 0);
        }
      }
      int rl0 = g * 16 + kg * 4;
#pragma unroll
      for (int r = 0; r < 4; ++r) {
        int row = row0 + rl0 + r;
        if (row < M) yl[rl0 + r][c] = f2bf(acc[r] + btc);
      }
    }
    __syncthreads();

    int valid = min(64, M - row0);
    const uint4* src = (const uint4*)yl;
    uint4* dst = (uint4*)Y2 + (size_t)row0 * 16;
    for (int u = tid; u < valid * 16; u += 512) dst[u] = src[u];
  }
}

// ---------------------------------------------------------------------------
// Gather + LayerNorm. One wave per node; four 16-lane groups each gather one
// edge row as 16B dwordx4 (4 edges per VMEM instruction slot).
// ---------------------------------------------------------------------------
__global__ __launch_bounds__(256) void gather_ln_kernel(
    const uint* __restrict__ xw2, const uint* __restrict__ yd2,
    const float* __restrict__ dinv, const float* __restrict__ invcnt,
    const int* __restrict__ offsets, const int* __restrict__ deg,
    const uint* __restrict__ csr, void* __restrict__ out,
    const int* __restrict__ flag, int n_prot) {
  const int isf = *flag;
  const int node = (blockIdx.x * 256 + threadIdx.x) >> 6;
  const int lane = threadIdx.x & 63;
  const int grp = lane >> 4;  // 0..3 : edge sub-group
  const int li = lane & 15;   // cols [li*8, li*8+8)  (uint4 index li)
  if (node >= n_prot) return;
  const int s0 = offsets[node];
  const int s1 = offsets[node + 1];
  const int sm = s0 + deg[node];
  const float dn = dinv[node], ic = invcnt[node];

  float aP[8] = {0.f, 0.f, 0.f, 0.f, 0.f, 0.f, 0.f, 0.f};
  float aD[8] = {0.f, 0.f, 0.f, 0.f, 0.f, 0.f, 0.f, 0.f};

  const uint4* X4 = (const uint4*)xw2;
  const uint4* Y4 = (const uint4*)yd2;

#pragma unroll
  for (int part = 0; part < 2; ++part) {
    const uint4* T = part ? Y4 : X4;
    float* acc = part ? aD : aP;
    int a = part ? sm : s0;
    int b = part ? s1 : sm;
    for (int base = a; base < b;) {
      int m = min(64, b - base);
      uint ent = (lane < m) ? csr[base + lane] : 0u;
      int nb4 = m >> 2;
      int t = 0;
      for (; t + 4 <= nb4; t += 4) {  // 16 edges, 4 loads in flight per lane
        uint e0 = __shfl(ent, (t + 0) * 4 + grp);
        uint e1 = __shfl(ent, (t + 1) * 4 + grp);
        uint e2 = __shfl(ent, (t + 2) * 4 + grp);
        uint e3 = __shfl(ent, (t + 3) * 4 + grp);
        uint4 w0 = T[(size_t)e0 * 16 + li];
        uint4 w1 = T[(size_t)e1 * 16 + li];
        uint4 w2 = T[(size_t)e2 * 16 + li];
        uint4 w3 = T[(size_t)e3 * 16 + li];
        acc8(acc, w0);
        acc8(acc, w1);
        acc8(acc, w2);
        acc8(acc, w3);
      }
      for (; t < nb4; ++t) {
        uint e = __shfl(ent, t * 4 + grp);
        uint4 w = T[(size_t)e * 16 + li];
        acc8(acc, w);
      }
      int rem = m & 3;
      if (rem) {
        uint e = __shfl(ent, nb4 * 4 + grp);
        if (grp < rem) {
          uint4 w = T[(size_t)e * 16 + li];
          acc8(acc, w);
        }
      }
      base += m;
    }
  }

  // combine lists, reduce across the 4 groups (lanes ^16, ^32)
  float v[8];
#pragma unroll
  for (int i = 0; i < 8; ++i) v[i] = fmaf(dn, aP[i], ic * aD[i]);
#pragma unroll
  for (int i = 0; i < 8; ++i) {
    v[i] += __shfl_xor(v[i], 16);
    v[i] += __shfl_xor(v[i], 32);
  }

  // add x3' (read from out, in output dtype)
  if (isf) {
    const float4* xr = (const float4*)out + (size_t)node * 32 + li * 2;
    float4 x0 = xr[0], x1 = xr[1];
    v[0] += x0.x; v[1] += x0.y; v[2] += x0.z; v[3] += x0.w;
    v[4] += x1.x; v[5] += x1.y; v[6] += x1.z; v[7] += x1.w;
  } else {
    uint4 xr = ((const uint4*)out)[(size_t)node * 16 + li];
    float2 t0 = bf16x2(xr.x), t1 = bf16x2(xr.y);
    float2 t2 = bf16x2(xr.z), t3 = bf16x2(xr.w);
    v[0] += t0.x; v[1] += t0.y; v[2] += t1.x; v[3] += t1.y;
    v[4] += t2.x; v[5] += t2.y; v[6] += t3.x; v[7] += t3.y;
  }

  // LayerNorm over 128 cols (each li owns 8; reduce over 16 lanes)
  float s = 0.f, ss = 0.f;
#pragma unroll
  for (int i = 0; i < 8; ++i) {
    s += v[i];
    ss = fmaf(v[i], v[i], ss);
  }
#pragma unroll
  for (int off = 1; off < 16; off <<= 1) {
    s += __shfl_xor(s, off);
    ss += __shfl_xor(ss, off);
  }
  float mu = s * (1.0f / 128.0f);
  float var = ss * (1.0f / 128.0f) - mu * mu;
  float rs = rsqrtf(var + 1e-5f);
#pragma unroll
  for (int i = 0; i < 8; ++i) v[i] = (v[i] - mu) * rs;

  if (isf) {
    if (grp < 2) {  // 32 lanes cover the 512B row
      float4 o = (grp == 0) ? make_float4(v[0], v[1], v[2], v[3])
                            : make_float4(v[4], v[5], v[6], v[7]);
      ((float4*)out)[(size_t)node * 32 + li * 2 + grp] = o;
    }
  } else {
    if (grp == 0) {
      uint4 o;
      o.x = pack_bf16x2(v[0], v[1]);
      o.y = pack_bf16x2(v[2], v[3]);
      o.z = pack_bf16x2(v[4], v[5]);
      o.w = pack_bf16x2(v[6], v[7]);
      ((uint4*)out)[(size_t)node * 16 + li] = o;
    }
  }
}

// ---------------------------------------------------------------------------
extern "C" void kernel_launch(void* const* d_in, const int* in_sizes, int n_in,
                              void* d_out, int out_size, void* d_ws,
                              size_t ws_size, hipStream_t stream) {
  const void* x_prot = d_in[0];
  const void* x_drug = d_in[1];
  const void* W_gcn = d_in[2];
  const void* b_gcn = d_in[3];
  const void* W_td = d_in[4];
  const void* b_td = d_in[5];
  const void* W_pr = d_in[6];
  const void* b_pr = d_in[7];
  const int* ppi = (const int*)d_in[8];
  const int* dti_drug = (const int*)d_in[9];
  const int* dti_prot = (const int*)d_in[10];

  int n_prot = in_sizes[0] / D;
  int n_drug = in_sizes[1] / D;
  int e_ppi = in_sizes[8] / 2;
  int e_dti = in_sizes[9];
  int e_tot = e_ppi + e_dti;
  int nb = (n_prot + 255) / 256;
  int nbk = (n_prot + NPBK - 1) / NPBK;  // coarse buckets (== nb here)

  char* ws = (char*)d_ws;
  size_t off = 0;
  auto alloc = [&](size_t bytes) {
    void* p = ws + off;
    off = (off + bytes + 255) & ~(size_t)255;
    return p;
  };
  int* flag = (int*)alloc(256);
  uint* xw2 = (uint*)alloc((size_t)n_prot * 64 * 4);  // 25.6 MB (pre-scaled)
  uint* yd2 = (uint*)alloc((size_t)n_drug * 64 * 4);  //  5.1 MB
  int* deg = (int*)alloc((size_t)n_prot * 4);
  int* cnt = (int*)alloc((size_t)n_prot * 4);
  float* dinv = (float*)alloc((size_t)n_prot * 4);
  float* invcnt = (float*)alloc((size_t)n_prot * 4);
  int* offsets = (int*)alloc((size_t)(n_prot + 1) * 4);
  int* fposp = (int*)alloc((size_t)n_prot * 4);
  int* fposd = (int*)alloc((size_t)n_prot * 4);
  int* bsum = (int*)alloc((size_t)nb * 4);
  int* gbh = (int*)alloc((size_t)NBMAX * 4);
  int* bbase = (int*)alloc((size_t)(NBMAX + 1) * 4);
  int* bcur = (int*)alloc((size_t)NBMAX * 4);
  uint* csr = (uint*)alloc((size_t)e_tot * 4);  // 9.6 MB

  if (off > ws_size) return;  // insufficient workspace: bail cleanly

  // Partitioned-edge scratch aliases xw2: place_count finishes before
  // gemm_prot_mfma writes xw2 (same stream), and e_tot*4 <= n_prot*256 here.
  uint* P = xw2;
  bool fast_fill = (n_prot <= (1 << 17)) && (n_drug <= (1 << 17)) &&
                   (nbk <= NBMAX) && ((size_t)e_tot * 4 <= (size_t)n_prot * 256);

  detect_kernel<<<1, 256, 0, stream>>>((const uint*)x_prot, 4096, flag);

  if (fast_fill) {
    hipMemsetAsync(gbh, 0, (size_t)NBMAX * 4, stream);
    bucket_hist_kernel<<<(e_tot + 8191) / 8192, 256, 0, stream>>>(
        ppi + e_ppi, dti_prot, gbh, e_ppi, e_dti, n_prot, nbk);
    bucket_scan_kernel<<<1, NBMAX, 0, stream>>>(gbh, bbase, bcur, nbk);
    partition_kernel<<<(e_tot + TILE_A - 1) / TILE_A, 256, 0, stream>>>(
        ppi, ppi + e_ppi, dti_drug, dti_prot, bcur, P, e_ppi, e_dti, n_prot,
        nbk);
    place_count_kernel<<<nbk, 1024, 0, stream>>>(
        P, bbase, csr, deg, dinv, invcnt, offsets, n_prot, nbk);
  } else {
    hipMemsetAsync(deg, 0, (size_t)n_prot * 4, stream);
    hipMemsetAsync(cnt, 0, (size_t)n_prot * 4, stream);
    hipMemsetAsync(fposp, 0, (size_t)n_prot * 4, stream);
    hipMemsetAsync(fposd, 0, (size_t)n_prot * 4, stream);
    count_kernel<<<(e_tot + 255) / 256, 256, 0, stream>>>(
        ppi + e_ppi, dti_prot, deg, cnt, e_ppi, e_dti, n_prot);
    block_sum_kernel<<<nb, 256, 0, stream>>>(deg, cnt, n_prot, dinv, invcnt,
                                             bsum);
    scan_bsums_kernel<<<1, 1024, 0, stream>>>(bsum, nb);
    scan_final_kernel<<<nb, 256, 0, stream>>>(deg, cnt, bsum, offsets, n_prot);
    fill_kernel<<<(e_tot + 255) / 256, 256, 0, stream>>>(
        ppi, ppi + e_ppi, dti_drug, dti_prot, offsets, deg, fposp, fposd, csr,
        e_ppi, e_dti, n_prot);
  }

  int nbat_p = (n_prot + 63) / 64;
  int grid_p = nbat_p < 512 ? nbat_p : 512;
  gemm_prot_mfma<<<grid_p, 512, 0, stream>>>(x_prot, W_gcn, W_pr, b_gcn, b_pr,
                                             dinv, xw2, d_out, flag, n_prot);
  int nbat_d = (n_drug + 63) / 64;
  int grid_d = nbat_d < 512 ? nbat_d : 512;
  gemm_drug_mfma<<<grid_d, 512, 0, stream>>>(x_drug, W_td, b_td, yd2, flag,
                                             n_drug);

  gather_ln_kernel<<<(n_prot + 3) / 4, 256, 0, stream>>>(
      xw2, yd2, dinv, invcnt, offsets, deg, csr, d_out, flag, n_prot);
}

// Round 8
// 308.301 us; speedup vs baseline: 1.3466x; 1.0335x over previous
//
#include <hip/hip_runtime.h>
#include <hip/hip_bf16.h>

#define D 128
#define NPBK 256     // nodes per coarse bucket (partition/placement)
#define NBMAX 512    // max coarse buckets supported by LDS arrays
#define TILE_A 4096  // edges per partition block (256 thr x 16)
#define SEGMAX 8192  // max bucket segment for LDS-staged csr writeout

typedef unsigned int uint;
typedef unsigned short ushort;
typedef __attribute__((ext_vector_type(8))) short short8;
typedef __attribute__((ext_vector_type(4))) float f32x4;

// unpack a bf16x2 (as uint) into two floats: x = low half, y = high half
static __device__ __forceinline__ float2 bf16x2(uint u) {
  float2 r;
  r.x = __uint_as_float(u << 16);
  r.y = __uint_as_float(u & 0xffff0000u);
  return r;
}

static __device__ __forceinline__ uint pack_bf16x2(float a, float b) {
  __hip_bfloat162 o;
  o.x = __float2bfloat16(a);
  o.y = __float2bfloat16(b);
  return *reinterpret_cast<uint*>(&o);
}

static __device__ __forceinline__ ushort f2bf(float f) {
  __hip_bfloat16 h = __float2bfloat16(f);
  return *reinterpret_cast<ushort*>(&h);
}
static __device__ __forceinline__ float bf2f(ushort u) {
  return __uint_as_float(((uint)u) << 16);
}

// accumulate 8 bf16 values (packed in a uint4) into acc[0..7]
static __device__ __forceinline__ void acc8(float* acc, uint4 v) {
  float2 t0 = bf16x2(v.x), t1 = bf16x2(v.y);
  float2 t2 = bf16x2(v.z), t3 = bf16x2(v.w);
  acc[0] += t0.x; acc[1] += t0.y;
  acc[2] += t1.x; acc[3] += t1.y;
  acc[4] += t2.x; acc[5] += t2.y;
  acc[6] += t3.x; acc[7] += t3.y;
}

// ---------------------------------------------------------------------------
// Standalone detect (fallback path only). flag=1 means fp32 storage.
// ---------------------------------------------------------------------------
__global__ void detect_kernel(const uint* __restrict__ x, int n_words,
                              int* __restrict__ flag) {
  __shared__ float smax[256];
  float m = 0.f;
  for (int i = threadIdx.x; i < n_words; i += 256) {
    float2 v = bf16x2(x[i]);
    float a = fabsf(v.x), b = fabsf(v.y);
    if (!(a <= 1e30f)) a = 1e30f;
    if (!(b <= 1e30f)) b = 1e30f;
    m = fmaxf(m, fmaxf(a, b));
  }
  smax[threadIdx.x] = m;
  __syncthreads();
  for (int s = 128; s > 0; s >>= 1) {
    if (threadIdx.x < s)
      smax[threadIdx.x] = fmaxf(smax[threadIdx.x], smax[threadIdx.x + s]);
    __syncthreads();
  }
  if (threadIdx.x == 0) *flag = (smax[0] > 1e6f) ? 1 : 0;
}

// ---------------------------------------------------------------------------
// FAST PATH pass 0: coarse bucket histogram (LDS) -> global bucket totals.
// Block 0 additionally performs dtype detection (folds detect_kernel).
// ---------------------------------------------------------------------------
__global__ __launch_bounds__(256) void bucket_hist_kernel(
    const int* __restrict__ ppi_col, const int* __restrict__ dti_prot,
    int* __restrict__ gbh, const uint* __restrict__ xdet,
    int* __restrict__ flag, int e_ppi, int e_dti, int n_prot, int nbk) {
  __shared__ int hist[NBMAX];
  __shared__ float smax[256];
  const int tid = threadIdx.x;

  if (blockIdx.x == 0) {  // fused dtype detect (4096 words of x_prot)
    float m = 0.f;
    for (int i = tid; i < 4096; i += 256) {
      float2 v = bf16x2(xdet[i]);
      float a = fabsf(v.x), b = fabsf(v.y);
      if (!(a <= 1e30f)) a = 1e30f;
      if (!(b <= 1e30f)) b = 1e30f;
      m = fmaxf(m, fmaxf(a, b));
    }
    smax[tid] = m;
    __syncthreads();
    for (int s = 128; s > 0; s >>= 1) {
      if (tid < s) smax[tid] = fmaxf(smax[tid], smax[tid + s]);
      __syncthreads();
    }
    if (tid == 0) *flag = (smax[0] > 1e6f) ? 1 : 0;
  }

  for (int b = tid; b < nbk; b += 256) hist[b] = 0;
  __syncthreads();
  const int e_tot = e_ppi + e_dti;
  const int base = blockIdx.x * 8192;
#pragma unroll 4
  for (int j = 0; j < 32; ++j) {
    int i = base + j * 256 + tid;
    if (i < e_tot) {
      int dst = (i < e_ppi) ? ppi_col[i] : dti_prot[i - e_ppi];
      if ((unsigned)dst < (unsigned)n_prot) atomicAdd(&hist[dst >> 8], 1);
    }
  }
  __syncthreads();
  for (int b = tid; b < nbk; b += 256) {
    int h = hist[b];
    if (h) atomicAdd(&gbh[b], h);
  }
}

// ---------------------------------------------------------------------------
// FAST PATH pass A: partition edges into coarse dst-buckets (256 nodes each).
// Packed entry: src(17b) | type(1b)<<17 | (dst&255)<<18 -> one uint.
// In-block LDS counting sort, then COALESCED copy-out. Bucket bases are
// derived in-block from a scan of gbh (no separate bucket_scan kernel);
// gcur is a zero-based per-bucket allocation cursor.
// ---------------------------------------------------------------------------
__global__ __launch_bounds__(256) void partition_kernel(
    const int* __restrict__ ppi_row, const int* __restrict__ ppi_col,
    const int* __restrict__ dti_drug, const int* __restrict__ dti_prot,
    const int* __restrict__ gbh, int* __restrict__ gcur, uint* __restrict__ P,
    int e_ppi, int e_dti, int n_prot, int nb) {
  __shared__ int hist[NBMAX];
  __shared__ int sh[NBMAX];
  __shared__ int lbase[NBMAX];
  __shared__ int gbase[NBMAX];
  __shared__ int cur[NBMAX];
  __shared__ int totS;
  __shared__ uint entL[TILE_A];    // 16 KB
  __shared__ ushort bktL[TILE_A];  // 8 KB
  const int tid = threadIdx.x;
  const int t2 = tid + 256;
  const int base = blockIdx.x * TILE_A;
  const int e_tot = e_ppi + e_dti;

  hist[tid] = 0;
  hist[t2] = 0;
  __syncthreads();

  uint sv[16];
  int dv[16];
#pragma unroll
  for (int j = 0; j < 16; ++j) {
    int i = base + j * 256 + tid;
    int d = -1;
    uint s = 0;
    if (i < e_tot) {
      int src, dst, type;
      if (i < e_ppi) {
        src = ppi_row[i];
        dst = ppi_col[i];
        type = 0;
      } else {
        int k = i - e_ppi;
        src = dti_drug[k];
        dst = dti_prot[k];
        type = 1;
      }
      if ((unsigned)dst < (unsigned)n_prot) {
        d = dst;
        s = (uint)src | ((uint)type << 17);
        atomicAdd(&hist[dst >> 8], 1);
      }
    }
    sv[j] = s;
    dv[j] = d;
  }
  __syncthreads();

  // inclusive scan of hist (NBMAX slots, 256 threads x 2)
  sh[tid] = hist[tid];
  sh[t2] = hist[t2];
  __syncthreads();
  for (int ofs = 1; ofs < NBMAX; ofs <<= 1) {
    int a0 = (tid >= ofs) ? sh[tid - ofs] : 0;
    int a1 = (t2 >= ofs) ? sh[t2 - ofs] : 0;
    __syncthreads();
    sh[tid] += a0;
    sh[t2] += a1;
    __syncthreads();
  }
  for (int b = tid; b < NBMAX; b += 256) {
    int lb = sh[b] - hist[b];
    lbase[b] = lb;
    cur[b] = lb;
  }
  if (tid == 0) totS = sh[NBMAX - 1];
  __syncthreads();

  // inclusive scan of gbh -> global bucket bases
  sh[tid] = (tid < nb) ? gbh[tid] : 0;
  sh[t2] = (t2 < nb) ? gbh[t2] : 0;
  __syncthreads();
  for (int ofs = 1; ofs < NBMAX; ofs <<= 1) {
    int a0 = (tid >= ofs) ? sh[tid - ofs] : 0;
    int a1 = (t2 >= ofs) ? sh[t2 - ofs] : 0;
    __syncthreads();
    sh[tid] += a0;
    sh[t2] += a1;
    __syncthreads();
  }
  for (int b = tid; b < NBMAX; b += 256) {
    int h = hist[b];
    gbase[b] = h ? ((b ? sh[b - 1] : 0) + atomicAdd(&gcur[b], h)) : 0;
  }
  __syncthreads();

  // scatter into LDS staging, sorted by bucket
#pragma unroll
  for (int j = 0; j < 16; ++j) {
    if (dv[j] >= 0) {
      int b = dv[j] >> 8;
      int r = atomicAdd(&cur[b], 1);
      entL[r] = sv[j] | ((uint)(dv[j] & (NPBK - 1)) << 18);
      bktL[r] = (ushort)b;
    }
  }
  __syncthreads();

  // coalesced copy-out: run of bucket b occupies consecutive u and
  // consecutive global addresses gbase[b] + (u - lbase[b]).
  const int tot = totS;
  for (int u = tid; u < tot; u += 256) {
    int b = bktL[u];
    P[gbase[b] + (u - lbase[b])] = entL[u];
  }
}

// ---------------------------------------------------------------------------
// FAST PATH pass B (fused): one block per bucket.
//  0) scan gbh in LDS -> this bucket's [start,end)
//  1) stream P segment: per-node deg/cnt histogram in LDS
//  2) LDS scan -> per-node offsets; write deg/dinv/invcnt/offsets sequentially
//  3) re-read P (L2-hot), scatter into LDS srt[], stream csr out COALESCED
// ---------------------------------------------------------------------------
__global__ __launch_bounds__(1024) void place_count_kernel(
    const uint* __restrict__ P, const int* __restrict__ gbh,
    uint* __restrict__ csr, int* __restrict__ deg, float* __restrict__ dinv,
    float* __restrict__ invcnt, int* __restrict__ offsets, int n_prot,
    int nbk) {
  __shared__ int degL[NPBK], cntL[NPBK];
  __shared__ int cp[NPBK], cd[NPBK];
  __shared__ int sc[NPBK];
  __shared__ int gsh[NBMAX];
  __shared__ int startS, endS;
  __shared__ uint srt[SEGMAX];  // 32 KB
  const int tid = threadIdx.x;
  const int b = blockIdx.x;
  const int node0 = b * NPBK;
  const int nn = min(NPBK, n_prot - node0);

  // scan gbh -> [start, end) of this bucket
  if (tid < NBMAX) gsh[tid] = (tid < nbk) ? gbh[tid] : 0;
  __syncthreads();
  for (int ofs = 1; ofs < NBMAX; ofs <<= 1) {
    int t = 0;
    if (tid < NBMAX && tid >= ofs) t = gsh[tid - ofs];
    __syncthreads();
    if (tid < NBMAX) gsh[tid] += t;
    __syncthreads();
  }
  if (tid == 0) {
    startS = b ? gsh[b - 1] : 0;
    endS = gsh[b];
  }
  if (tid < NPBK) {
    degL[tid] = 0;
    cntL[tid] = 0;
  }
  __syncthreads();
  const int start = startS, end = endS;
  const int nseg = end - start;

  for (int i = start + tid; i < end; i += 1024) {
    uint p = P[i];
    int nl = (int)(p >> 18);
    if ((p >> 17) & 1u)
      atomicAdd(&cntL[nl], 1);
    else
      atomicAdd(&degL[nl], 1);
  }
  __syncthreads();

  // inclusive scan over per-node totals (256 entries), local 0-based
  int v = 0;
  if (tid < NPBK) {
    v = (tid < nn) ? (degL[tid] + cntL[tid]) : 0;
    sc[tid] = v;
  }
  __syncthreads();
  for (int ofs = 1; ofs < NPBK; ofs <<= 1) {
    int t = 0;
    if (tid < NPBK && tid >= ofs) t = sc[tid - ofs];
    __syncthreads();
    if (tid < NPBK) sc[tid] += t;
    __syncthreads();
  }
  if (tid < nn) {
    int d = degL[tid], c = cntL[tid];
    int lexcl = sc[tid] - v;  // local position within segment
    int node = node0 + tid;
    offsets[node] = start + lexcl;
    deg[node] = d;
    dinv[node] = rsqrtf((float)(d + 1));  // +1 self-loop
    invcnt[node] = 1.0f / fmaxf((float)c, 1.0f);
    cp[tid] = lexcl;
    cd[tid] = lexcl + d;
  }
  if (b == nbk - 1 && tid == 0) offsets[n_prot] = end;
  __syncthreads();

  if (nseg <= SEGMAX) {
    // sort into LDS, then coalesced writeout
    for (int i = start + tid; i < end; i += 1024) {
      uint p = P[i];  // L2-hot re-read
      int nl = (int)(p >> 18);
      int pos =
          ((p >> 17) & 1u) ? atomicAdd(&cd[nl], 1) : atomicAdd(&cp[nl], 1);
      srt[pos] = p & 0x1ffffu;
    }
    __syncthreads();
    for (int u = tid; u < nseg; u += 1024) csr[start + u] = srt[u];
  } else {
    // oversized segment: direct scattered writes (window still L2-resident)
    for (int i = start + tid; i < end; i += 1024) {
      uint p = P[i];
      int nl = (int)(p >> 18);
      int pos =
          ((p >> 17) & 1u) ? atomicAdd(&cd[nl], 1) : atomicAdd(&cp[nl], 1);
      csr[start + pos] = p & 0x1ffffu;
    }
  }
}

// ---------------------------------------------------------------------------
// FALLBACK path kernels (used only when packing guards fail).
// ---------------------------------------------------------------------------
__global__ void count_kernel(const int* __restrict__ ppi_col,
                             const int* __restrict__ dti_prot,
                             int* __restrict__ deg, int* __restrict__ cnt,
                             int e_ppi, int e_dti, int n_prot) {
  int i = blockIdx.x * blockDim.x + threadIdx.x;
  if (i < e_ppi) {
    int c = ppi_col[i];
    if ((unsigned)c < (unsigned)n_prot) atomicAdd(&deg[c], 1);
  } else if (i < e_ppi + e_dti) {
    int c = dti_prot[i - e_ppi];
    if ((unsigned)c < (unsigned)n_prot) atomicAdd(&cnt[c], 1);
  }
}

__global__ void block_sum_kernel(const int* __restrict__ deg,
                                 const int* __restrict__ cnt, int n,
                                 float* __restrict__ dinv,
                                 float* __restrict__ invcnt,
                                 int* __restrict__ bsum) {
  __shared__ int sh[256];
  int i = blockIdx.x * 256 + threadIdx.x;
  int t = 0;
  if (i < n) {
    int d = deg[i], c = cnt[i];
    dinv[i] = rsqrtf((float)(d + 1));  // +1 self-loop
    invcnt[i] = 1.0f / fmaxf((float)c, 1.0f);
    t = d + c;
  }
  sh[threadIdx.x] = t;
  __syncthreads();
  for (int s = 128; s > 0; s >>= 1) {
    if (threadIdx.x < s) sh[threadIdx.x] += sh[threadIdx.x + s];
    __syncthreads();
  }
  if (threadIdx.x == 0) bsum[blockIdx.x] = sh[0];
}

__global__ void scan_bsums_kernel(int* __restrict__ bsum, int nb) {
  __shared__ int sh[1024];
  __shared__ int carry;
  int tid = threadIdx.x;
  if (tid == 0) carry = 0;
  __syncthreads();
  for (int base = 0; base < nb; base += 1024) {
    int i = base + tid;
    int v = (i < nb) ? bsum[i] : 0;
    sh[tid] = v;
    __syncthreads();
    for (int ofs = 1; ofs < 1024; ofs <<= 1) {
      int t = (tid >= ofs) ? sh[tid - ofs] : 0;
      __syncthreads();
      sh[tid] += t;
      __syncthreads();
    }
    if (i < nb) bsum[i] = carry + sh[tid] - v;  // exclusive
    int total = sh[1023];
    __syncthreads();
    if (tid == 0) carry += total;
    __syncthreads();
  }
}

__global__ void scan_final_kernel(const int* __restrict__ deg,
                                  const int* __restrict__ cnt,
                                  const int* __restrict__ bbase,
                                  int* __restrict__ offsets, int n) {
  __shared__ int sh[256];
  int tid = threadIdx.x;
  int i = blockIdx.x * 256 + tid;
  int v = (i < n) ? deg[i] + cnt[i] : 0;
  sh[tid] = v;
  __syncthreads();
  for (int ofs = 1; ofs < 256; ofs <<= 1) {
    int t = (tid >= ofs) ? sh[tid - ofs] : 0;
    __syncthreads();
    sh[tid] += t;
    __syncthreads();
  }
  if (i < n) {
    int excl = bbase[blockIdx.x] + sh[tid] - v;
    offsets[i] = excl;
    if (i == n - 1) offsets[n] = excl + v;
  }
}

__global__ void fill_kernel(const int* __restrict__ ppi_row,
                            const int* __restrict__ ppi_col,
                            const int* __restrict__ dti_drug,
                            const int* __restrict__ dti_prot,
                            const int* __restrict__ offsets,
                            const int* __restrict__ deg,
                            int* __restrict__ fposp, int* __restrict__ fposd,
                            uint* __restrict__ csr, int e_ppi, int e_dti,
                            int n_prot) {
  int i = blockIdx.x * blockDim.x + threadIdx.x;
  if (i < e_ppi) {
    int dst = ppi_col[i];
    if ((unsigned)dst >= (unsigned)n_prot) return;
    int pos = offsets[dst] + atomicAdd(&fposp[dst], 1);
    csr[pos] = (uint)ppi_row[i];
  } else if (i < e_ppi + e_dti) {
    int j = i - e_ppi;
    int dst = dti_prot[j];
    if ((unsigned)dst >= (unsigned)n_prot) return;
    int pos = offsets[dst] + deg[dst] + atomicAdd(&fposd[dst], 1);
    csr[pos] = (uint)dti_drug[j];
  }
}

// ---------------------------------------------------------------------------
// MFMA GEMM bodies (shared LDS buffers passed in). fp32 x handled via hi/lo
// bf16 split (x = hi + lo).
// ---------------------------------------------------------------------------
static __device__ void gemm_prot_body(
    uint4 (*aF)[4][2][64], ushort (*xwl)[128], const void* __restrict__ X,
    const void* __restrict__ Wg, const void* __restrict__ Wp,
    const void* __restrict__ bg, const void* __restrict__ bp,
    const float* __restrict__ dinv, uint* __restrict__ xw2,
    void* __restrict__ outx3, int isf, int M, int bid, int nblk) {
  const int tid = threadIdx.x;
  const int wv = tid >> 6, lane = tid & 63;
  const int cl = lane & 15, kg = lane >> 4;
  const int c = wv * 16 + cl;  // this wave's output column (0..127)

  short8 bG[4], bP[4];
#pragma unroll
  for (int kt = 0; kt < 4; ++kt) {
    int k0 = kt * 32 + 8 * kg;
    short8 fg, fp;
    if (isf) {
      const float* WgF = (const float*)Wg;
      const float* WpF = (const float*)Wp;
#pragma unroll
      for (int j = 0; j < 8; ++j) {
        fg[j] = (short)f2bf(WgF[(k0 + j) * D + c]);
        fp[j] = (short)f2bf(WpF[(k0 + j) * D + c]);
      }
    } else {
      const ushort* WgH = (const ushort*)Wg;
      const ushort* WpH = (const ushort*)Wp;
#pragma unroll
      for (int j = 0; j < 8; ++j) {
        fg[j] = (short)WgH[(k0 + j) * D + c];
        fp[j] = (short)WpH[(k0 + j) * D + c];
      }
    }
    bG[kt] = fg;
    bP[kt] = fp;
  }
  float btc;
  {
    float a = isf ? ((const float*)bg)[c] : bf2f(((const ushort*)bg)[c]);
    float b = isf ? ((const float*)bp)[c] : bf2f(((const ushort*)bp)[c]);
    btc = a + b + 1e-6f;
  }

  for (int row0 = bid * 64; row0 < M; row0 += nblk * 64) {
    for (int u = tid; u < 1024; u += 512) {
      int row = u >> 4, kc = u & 15;
      int grow = row0 + row;
      uint4 hi = make_uint4(0, 0, 0, 0), lo = make_uint4(0, 0, 0, 0);
      if (isf) {
        if (grow < M) {
          const float4* Xf = (const float4*)X;
          float4 v0 = Xf[(size_t)grow * 32 + kc * 2];
          float4 v1 = Xf[(size_t)grow * 32 + kc * 2 + 1];
          float v[8] = {v0.x, v0.y, v0.z, v0.w, v1.x, v1.y, v1.z, v1.w};
          uint hw[4], lw[4];
#pragma unroll
          for (int j = 0; j < 4; ++j) {
            ushort h0 = f2bf(v[2 * j]), h1 = f2bf(v[2 * j + 1]);
            ushort l0 = f2bf(v[2 * j] - bf2f(h0));
            ushort l1 = f2bf(v[2 * j + 1] - bf2f(h1));
            hw[j] = (uint)h0 | ((uint)h1 << 16);
            lw[j] = (uint)l0 | ((uint)l1 << 16);
          }
          hi = make_uint4(hw[0], hw[1], hw[2], hw[3]);
          lo = make_uint4(lw[0], lw[1], lw[2], lw[3]);
        }
      } else {
        if (grow < M) hi = ((const uint4*)X)[(size_t)grow * 16 + kc];
      }
      int ln = (kc & 3) * 16 + (row & 15);
      int g = row >> 4, kt = kc >> 2;
      aF[g][kt][0][ln] = hi;
      if (isf) aF[g][kt][1][ln] = lo;
    }
    __syncthreads();

#pragma unroll
    for (int g = 0; g < 4; ++g) {
      f32x4 accG = {0.f, 0.f, 0.f, 0.f};
      f32x4 accP = {0.f, 0.f, 0.f, 0.f};
      uint4 aH[4];
#pragma unroll
      for (int kt = 0; kt < 4; ++kt) aH[kt] = aF[g][kt][0][lane];
#pragma unroll
      for (int kt = 0; kt < 4; ++kt) {
        short8 a = __builtin_bit_cast(short8, aH[kt]);
        accG = __builtin_amdgcn_mfma_f32_16x16x32_bf16(a, bG[kt], accG, 0, 0, 0);
        accP = __builtin_amdgcn_mfma_f32_16x16x32_bf16(a, bP[kt], accP, 0, 0, 0);
      }
      if (isf) {
        uint4 aL[4];
#pragma unroll
        for (int kt = 0; kt < 4; ++kt) aL[kt] = aF[g][kt][1][lane];
#pragma unroll
        for (int kt = 0; kt < 4; ++kt) {
          short8 a = __builtin_bit_cast(short8, aL[kt]);
          accG = __builtin_amdgcn_mfma_f32_16x16x32_bf16(a, bG[kt], accG, 0, 0, 0);
          accP = __builtin_amdgcn_mfma_f32_16x16x32_bf16(a, bP[kt], accP, 0, 0, 0);
        }
      }
      int rl0 = g * 16 + kg * 4;
#pragma unroll
      for (int r = 0; r < 4; ++r) {
        int row = row0 + rl0 + r;
        if (row < M) {
          float dn = dinv[row];
          float gv = accG[r], pv = accP[r];
          xwl[rl0 + r][c] = f2bf(gv * dn);
          float ov = fmaf(gv, dn * dn, pv + btc);
          if (isf)
            ((float*)outx3)[(size_t)row * D + c] = ov;
          else
            ((ushort*)outx3)[(size_t)row * D + c] = f2bf(ov);
        }
      }
    }
    __syncthreads();

    int valid = min(64, M - row0);
    const uint4* src = (const uint4*)xwl;
    uint4* dst = (uint4*)xw2 + (size_t)row0 * 16;
    for (int u = tid; u < valid * 16; u += 512) dst[u] = src[u];
  }
}

static __device__ void gemm_drug_body(uint4 (*aF)[4][2][64], ushort (*yl)[128],
                                      const void* __restrict__ X,
                                      const void* __restrict__ W,
                                      const void* __restrict__ bias,
                                      uint* __restrict__ Y2, int isf, int M,
                                      int bid, int nblk) {
  const int tid = threadIdx.x;
  const int wv = tid >> 6, lane = tid & 63;
  const int cl = lane & 15, kg = lane >> 4;
  const int c = wv * 16 + cl;

  short8 bT[4];
#pragma unroll
  for (int kt = 0; kt < 4; ++kt) {
    int k0 = kt * 32 + 8 * kg;
    short8 ft;
    if (isf) {
      const float* Wf = (const float*)W;
#pragma unroll
      for (int j = 0; j < 8; ++j) ft[j] = (short)f2bf(Wf[(k0 + j) * D + c]);
    } else {
      const ushort* Wh = (const ushort*)W;
#pragma unroll
      for (int j = 0; j < 8; ++j) ft[j] = (short)Wh[(k0 + j) * D + c];
    }
    bT[kt] = ft;
  }
  float btc = isf ? ((const float*)bias)[c] : bf2f(((const ushort*)bias)[c]);

  for (int row0 = bid * 64; row0 < M; row0 += nblk * 64) {
    for (int u = tid; u < 1024; u += 512) {
      int row = u >> 4, kc = u & 15;
      int grow = row0 + row;
      uint4 hi = make_uint4(0, 0, 0, 0), lo = make_uint4(0, 0, 0, 0);
      if (isf) {
        if (grow < M) {
          const float4* Xf = (const float4*)X;
          float4 v0 = Xf[(size_t)grow * 32 + kc * 2];
          float4 v1 = Xf[(size_t)grow * 32 + kc * 2 + 1];
          float v[8] = {v0.x, v0.y, v0.z, v0.w, v1.x, v1.y, v1.z, v1.w};
          uint hw[4], lw[4];
#pragma unroll
          for (int j = 0; j < 4; ++j) {
            ushort h0 = f2bf(v[2 * j]), h1 = f2bf(v[2 * j + 1]);
            ushort l0 = f2bf(v[2 * j] - bf2f(h0));
            ushort l1 = f2bf(v[2 * j + 1] - bf2f(h1));
            hw[j] = (uint)h0 | ((uint)h1 << 16);
            lw[j] = (uint)l0 | ((uint)l1 << 16);
          }
          hi = make_uint4(hw[0], hw[1], hw[2], hw[3]);
          lo = make_uint4(lw[0], lw[1], lw[2], lw[3]);
        }
      } else {
        if (grow < M) hi = ((const uint4*)X)[(size_t)grow * 16 + kc];
      }
      int ln = (kc & 3) * 16 + (row & 15);
      int g = row >> 4, kt = kc >> 2;
      aF[g][kt][0][ln] = hi;
      if (isf) aF[g][kt][1][ln] = lo;
    }
    __syncthreads();

#pragma unroll
    for (int g = 0; g < 4; ++g) {
      f32x4 acc = {0.f, 0.f, 0.f, 0.f};
      uint4 aH[4];
#pragma unroll
      for (int kt = 0; kt < 4; ++kt) aH[kt] = aF[g][kt][0][lane];
#pragma unroll
      for (int kt = 0; kt < 4; ++kt) {
        short8 a = __builtin_bit_cast(short8, aH[kt]);
        acc = __builtin_amdgcn_mfma_f32_16x16x32_bf16(a, bT[kt], acc, 0, 0, 0);
      }
      if (isf) {
        uint4 aL[4];
#pragma unroll
        for (int kt = 0; kt < 4; ++kt) aL[kt] = aF[g][kt][1][lane];
#pragma unroll
        for (int kt = 0; kt < 4; ++kt) {
          short8 a = __builtin_bit_cast(short8, aL[kt]);
          acc = __builtin_amdgcn_mfma_f32_16x16x32_bf16(a, bT[kt], acc, 0, 0, 0);
        }
      }
      int rl0 = g * 16 + kg * 4;
#pragma unroll
      for (int r = 0; r < 4; ++r) {
        int row = row0 + rl0 + r;
        if (row < M) yl[rl0 + r][c] = f2bf(acc[r] + btc);
      }
    }
    __syncthreads();

    int valid = min(64, M - row0);
    const uint4* src = (const uint4*)yl;
    uint4* dst = (uint4*)Y2 + (size_t)row0 * 16;
    for (int u = tid; u < valid * 16; u += 512) dst[u] = src[u];
  }
}

// Fused GEMM dispatch: blocks [0,gp) = protein, [gp, gp+gd) = drug.
__global__ __launch_bounds__(512) void gemm_fused_kernel(
    const void* __restrict__ Xp, const void* __restrict__ Wg,
    const void* __restrict__ Wp, const void* __restrict__ bg,
    const void* __restrict__ bp, const float* __restrict__ dinv,
    uint* __restrict__ xw2, void* __restrict__ outx3, int Mp, int gp,
    const void* __restrict__ Xd, const void* __restrict__ Wt,
    const void* __restrict__ bt, uint* __restrict__ yd2, int Md,
    const int* __restrict__ flag) {
  __shared__ uint4 aF[4][4][2][64];  // 32 KB
  __shared__ ushort tb[64][128];     // 16 KB
  const int isf = *flag;
  if ((int)blockIdx.x < gp)
    gemm_prot_body(aF, tb, Xp, Wg, Wp, bg, bp, dinv, xw2, outx3, isf, Mp,
                   blockIdx.x, gp);
  else
    gemm_drug_body(aF, tb, Xd, Wt, bt, yd2, isf, Md, blockIdx.x - gp,
                   gridDim.x - gp);
}

// ---------------------------------------------------------------------------
// Gather + LayerNorm. One wave per node; four 16-lane groups each gather one
// edge row as 16B dwordx4 (4 edges per VMEM instruction slot).
// ---------------------------------------------------------------------------
__global__ __launch_bounds__(256) void gather_ln_kernel(
    const uint* __restrict__ xw2, const uint* __restrict__ yd2,
    const float* __restrict__ dinv, const float* __restrict__ invcnt,
    const int* __restrict__ offsets, const int* __restrict__ deg,
    const uint* __restrict__ csr, void* __restrict__ out,
    const int* __restrict__ flag, int n_prot) {
  const int isf = *flag;
  const int node = (blockIdx.x * 256 + threadIdx.x) >> 6;
  const int lane = threadIdx.x & 63;
  const int grp = lane >> 4;  // 0..3 : edge sub-group
  const int li = lane & 15;   // cols [li*8, li*8+8)  (uint4 index li)
  if (node >= n_prot) return;
  const int s0 = offsets[node];
  const int s1 = offsets[node + 1];
  const int sm = s0 + deg[node];
  const float dn = dinv[node], ic = invcnt[node];

  float aP[8] = {0.f, 0.f, 0.f, 0.f, 0.f, 0.f, 0.f, 0.f};
  float aD[8] = {0.f, 0.f, 0.f, 0.f, 0.f, 0.f, 0.f, 0.f};

  const uint4* X4 = (const uint4*)xw2;
  const uint4* Y4 = (const uint4*)yd2;

#pragma unroll
  for (int part = 0; part < 2; ++part) {
    const uint4* T = part ? Y4 : X4;
    float* acc = part ? aD : aP;
    int a = part ? sm : s0;
    int b = part ? s1 : sm;
    for (int base = a; base < b;) {
      int m = min(64, b - base);
      uint ent = (lane < m) ? csr[base + lane] : 0u;
      int nb4 = m >> 2;
      int t = 0;
      for (; t + 4 <= nb4; t += 4) {  // 16 edges, 4 loads in flight per lane
        uint e0 = __shfl(ent, (t + 0) * 4 + grp);
        uint e1 = __shfl(ent, (t + 1) * 4 + grp);
        uint e2 = __shfl(ent, (t + 2) * 4 + grp);
        uint e3 = __shfl(ent, (t + 3) * 4 + grp);
        uint4 w0 = T[(size_t)e0 * 16 + li];
        uint4 w1 = T[(size_t)e1 * 16 + li];
        uint4 w2 = T[(size_t)e2 * 16 + li];
        uint4 w3 = T[(size_t)e3 * 16 + li];
        acc8(acc, w0);
        acc8(acc, w1);
        acc8(acc, w2);
        acc8(acc, w3);
      }
      for (; t < nb4; ++t) {
        uint e = __shfl(ent, t * 4 + grp);
        uint4 w = T[(size_t)e * 16 + li];
        acc8(acc, w);
      }
      int rem = m & 3;
      if (rem) {
        uint e = __shfl(ent, nb4 * 4 + grp);
        if (grp < rem) {
          uint4 w = T[(size_t)e * 16 + li];
          acc8(acc, w);
        }
      }
      base += m;
    }
  }

  // combine lists, reduce across the 4 groups (lanes ^16, ^32)
  float v[8];
#pragma unroll
  for (int i = 0; i < 8; ++i) v[i] = fmaf(dn, aP[i], ic * aD[i]);
#pragma unroll
  for (int i = 0; i < 8; ++i) {
    v[i] += __shfl_xor(v[i], 16);
    v[i] += __shfl_xor(v[i], 32);
  }

  // add x3' (read from out, in output dtype)
  if (isf) {
    const float4* xr = (const float4*)out + (size_t)node * 32 + li * 2;
    float4 x0 = xr[0], x1 = xr[1];
    v[0] += x0.x; v[1] += x0.y; v[2] += x0.z; v[3] += x0.w;
    v[4] += x1.x; v[5] += x1.y; v[6] += x1.z; v[7] += x1.w;
  } else {
    uint4 xr = ((const uint4*)out)[(size_t)node * 16 + li];
    float2 t0 = bf16x2(xr.x), t1 = bf16x2(xr.y);
    float2 t2 = bf16x2(xr.z), t3 = bf16x2(xr.w);
    v[0] += t0.x; v[1] += t0.y; v[2] += t1.x; v[3] += t1.y;
    v[4] += t2.x; v[5] += t2.y; v[6] += t3.x; v[7] += t3.y;
  }

  // LayerNorm over 128 cols (each li owns 8; reduce over 16 lanes)
  float s = 0.f, ss = 0.f;
#pragma unroll
  for (int i = 0; i < 8; ++i) {
    s += v[i];
    ss = fmaf(v[i], v[i], ss);
  }
#pragma unroll
  for (int off = 1; off < 16; off <<= 1) {
    s += __shfl_xor(s, off);
    ss += __shfl_xor(ss, off);
  }
  float mu = s * (1.0f / 128.0f);
  float var = ss * (1.0f / 128.0f) - mu * mu;
  float rs = rsqrtf(var + 1e-5f);
#pragma unroll
  for (int i = 0; i < 8; ++i) v[i] = (v[i] - mu) * rs;

  if (isf) {
    if (grp < 2) {  // 32 lanes cover the 512B row
      float4 o = (grp == 0) ? make_float4(v[0], v[1], v[2], v[3])
                            : make_float4(v[4], v[5], v[6], v[7]);
      ((float4*)out)[(size_t)node * 32 + li * 2 + grp] = o;
    }
  } else {
    if (grp == 0) {
      uint4 o;
      o.x = pack_bf16x2(v[0], v[1]);
      o.y = pack_bf16x2(v[2], v[3]);
      o.z = pack_bf16x2(v[4], v[5]);
      o.w = pack_bf16x2(v[6], v[7]);
      ((uint4*)out)[(size_t)node * 16 + li] = o;
    }
  }
}

// ---------------------------------------------------------------------------
extern "C" void kernel_launch(void* const* d_in, const int* in_sizes, int n_in,
                              void* d_out, int out_size, void* d_ws,
                              size_t ws_size, hipStream_t stream) {
  const void* x_prot = d_in[0];
  const void* x_drug = d_in[1];
  const void* W_gcn = d_in[2];
  const void* b_gcn = d_in[3];
  const void* W_td = d_in[4];
  const void* b_td = d_in[5];
  const void* W_pr = d_in[6];
  const void* b_pr = d_in[7];
  const int* ppi = (const int*)d_in[8];
  const int* dti_drug = (const int*)d_in[9];
  const int* dti_prot = (const int*)d_in[10];

  int n_prot = in_sizes[0] / D;
  int n_drug = in_sizes[1] / D;
  int e_ppi = in_sizes[8] / 2;
  int e_dti = in_sizes[9];
  int e_tot = e_ppi + e_dti;
  int nb = (n_prot + 255) / 256;
  int nbk = (n_prot + NPBK - 1) / NPBK;  // coarse buckets (== nb here)

  char* ws = (char*)d_ws;
  size_t off = 0;
  auto alloc = [&](size_t bytes) {
    void* p = ws + off;
    off = (off + bytes + 255) & ~(size_t)255;
    return p;
  };
  int* flag = (int*)alloc(256);
  uint* xw2 = (uint*)alloc((size_t)n_prot * 64 * 4);  // 25.6 MB (pre-scaled)
  uint* yd2 = (uint*)alloc((size_t)n_drug * 64 * 4);  //  5.1 MB
  int* deg = (int*)alloc((size_t)n_prot * 4);
  int* cnt = (int*)alloc((size_t)n_prot * 4);
  float* dinv = (float*)alloc((size_t)n_prot * 4);
  float* invcnt = (float*)alloc((size_t)n_prot * 4);
  int* offsets = (int*)alloc((size_t)(n_prot + 1) * 4);
  int* fposp = (int*)alloc((size_t)n_prot * 4);
  int* fposd = (int*)alloc((size_t)n_prot * 4);
  int* bsum = (int*)alloc((size_t)nb * 4);
  int* gbh = (int*)alloc((size_t)NBMAX * 4);   // bucket totals
  int* gcur = (int*)alloc((size_t)NBMAX * 4);  // zero-based alloc cursors
  uint* csr = (uint*)alloc((size_t)e_tot * 4);  // 9.6 MB

  if (off > ws_size) return;  // insufficient workspace: bail cleanly

  // Partitioned-edge scratch aliases xw2: place_count finishes before
  // gemm writes xw2 (same stream), and e_tot*4 <= n_prot*256 here.
  uint* P = xw2;
  bool fast_fill = (n_prot <= (1 << 17)) && (n_drug <= (1 << 17)) &&
                   (nbk <= NBMAX) && ((size_t)e_tot * 4 <= (size_t)n_prot * 256);

  if (fast_fill) {
    // gbh and gcur are adjacent 2KB allocations -> one 4KB memset
    hipMemsetAsync(gbh, 0, (size_t)2 * NBMAX * 4, stream);
    bucket_hist_kernel<<<(e_tot + 8191) / 8192, 256, 0, stream>>>(
        ppi + e_ppi, dti_prot, gbh, (const uint*)x_prot, flag, e_ppi, e_dti,
        n_prot, nbk);
    partition_kernel<<<(e_tot + TILE_A - 1) / TILE_A, 256, 0, stream>>>(
        ppi, ppi + e_ppi, dti_drug, dti_prot, gbh, gcur, P, e_ppi, e_dti,
        n_prot, nbk);
    place_count_kernel<<<nbk, 1024, 0, stream>>>(
        P, gbh, csr, deg, dinv, invcnt, offsets, n_prot, nbk);
  } else {
    detect_kernel<<<1, 256, 0, stream>>>((const uint*)x_prot, 4096, flag);
    hipMemsetAsync(deg, 0, (size_t)n_prot * 4, stream);
    hipMemsetAsync(cnt, 0, (size_t)n_prot * 4, stream);
    hipMemsetAsync(fposp, 0, (size_t)n_prot * 4, stream);
    hipMemsetAsync(fposd, 0, (size_t)n_prot * 4, stream);
    count_kernel<<<(e_tot + 255) / 256, 256, 0, stream>>>(
        ppi + e_ppi, dti_prot, deg, cnt, e_ppi, e_dti, n_prot);
    block_sum_kernel<<<nb, 256, 0, stream>>>(deg, cnt, n_prot, dinv, invcnt,
                                             bsum);
    scan_bsums_kernel<<<1, 1024, 0, stream>>>(bsum, nb);
    scan_final_kernel<<<nb, 256, 0, stream>>>(deg, cnt, bsum, offsets, n_prot);
    fill_kernel<<<(e_tot + 255) / 256, 256, 0, stream>>>(
        ppi, ppi + e_ppi, dti_drug, dti_prot, offsets, deg, fposp, fposd, csr,
        e_ppi, e_dti, n_prot);
  }

  int nbat_p = (n_prot + 63) / 64;
  int grid_p = nbat_p < 512 ? nbat_p : 512;
  int nbat_d = (n_drug + 63) / 64;
  int grid_d = nbat_d < 512 ? nbat_d : 512;
  gemm_fused_kernel<<<grid_p + grid_d, 512, 0, stream>>>(
      x_prot, W_gcn, W_pr, b_gcn, b_pr, dinv, xw2, d_out, n_prot, grid_p,
      x_drug, W_td, b_td, yd2, n_drug, flag);

  gather_ln_kernel<<<(n_prot + 3) / 4, 256, 0, stream>>>(
      xw2, yd2, dinv, invcnt, offsets, deg, csr, d_out, flag, n_prot);
}

// Round 9
// 301.456 us; speedup vs baseline: 1.3772x; 1.0227x over previous
//
#include <hip/hip_runtime.h>
#include <hip/hip_bf16.h>

#define D 128
#define NPBK 256     // nodes per coarse bucket (partition/placement)
#define NBMAX 512    // max coarse buckets supported by LDS arrays
#define TILE_A 4096  // edges per partition block (256 thr x 16)
#define SEGMAX 8192  // max bucket segment for LDS-staged csr writeout

typedef unsigned int uint;
typedef unsigned short ushort;
typedef __attribute__((ext_vector_type(8))) short short8;
typedef __attribute__((ext_vector_type(4))) float f32x4;

// unpack a bf16x2 (as uint) into two floats: x = low half, y = high half
static __device__ __forceinline__ float2 bf16x2(uint u) {
  float2 r;
  r.x = __uint_as_float(u << 16);
  r.y = __uint_as_float(u & 0xffff0000u);
  return r;
}

static __device__ __forceinline__ uint pack_bf16x2(float a, float b) {
  __hip_bfloat162 o;
  o.x = __float2bfloat16(a);
  o.y = __float2bfloat16(b);
  return *reinterpret_cast<uint*>(&o);
}

static __device__ __forceinline__ ushort f2bf(float f) {
  __hip_bfloat16 h = __float2bfloat16(f);
  return *reinterpret_cast<ushort*>(&h);
}
static __device__ __forceinline__ float bf2f(ushort u) {
  return __uint_as_float(((uint)u) << 16);
}

// acc[0..7] += s * unpack_bf16x8(v)
static __device__ __forceinline__ void facc8(float* acc, uint4 v, float s) {
  float2 t0 = bf16x2(v.x), t1 = bf16x2(v.y);
  float2 t2 = bf16x2(v.z), t3 = bf16x2(v.w);
  acc[0] = fmaf(s, t0.x, acc[0]);
  acc[1] = fmaf(s, t0.y, acc[1]);
  acc[2] = fmaf(s, t1.x, acc[2]);
  acc[3] = fmaf(s, t1.y, acc[3]);
  acc[4] = fmaf(s, t2.x, acc[4]);
  acc[5] = fmaf(s, t2.y, acc[5]);
  acc[6] = fmaf(s, t3.x, acc[6]);
  acc[7] = fmaf(s, t3.y, acc[7]);
}

// ---------------------------------------------------------------------------
// Standalone detect (fallback path only). flag=1 means fp32 storage.
// ---------------------------------------------------------------------------
__global__ void detect_kernel(const uint* __restrict__ x, int n_words,
                              int* __restrict__ flag) {
  __shared__ float smax[256];
  float m = 0.f;
  for (int i = threadIdx.x; i < n_words; i += 256) {
    float2 v = bf16x2(x[i]);
    float a = fabsf(v.x), b = fabsf(v.y);
    if (!(a <= 1e30f)) a = 1e30f;
    if (!(b <= 1e30f)) b = 1e30f;
    m = fmaxf(m, fmaxf(a, b));
  }
  smax[threadIdx.x] = m;
  __syncthreads();
  for (int s = 128; s > 0; s >>= 1) {
    if (threadIdx.x < s)
      smax[threadIdx.x] = fmaxf(smax[threadIdx.x], smax[threadIdx.x + s]);
    __syncthreads();
  }
  if (threadIdx.x == 0) *flag = (smax[0] > 1e6f) ? 1 : 0;
}

// ---------------------------------------------------------------------------
// FAST PATH pass 0: coarse bucket histogram (LDS) -> global bucket totals.
// Block 0 additionally performs dtype detection (folds detect_kernel).
// ---------------------------------------------------------------------------
__global__ __launch_bounds__(256) void bucket_hist_kernel(
    const int* __restrict__ ppi_col, const int* __restrict__ dti_prot,
    int* __restrict__ gbh, const uint* __restrict__ xdet,
    int* __restrict__ flag, int e_ppi, int e_dti, int n_prot, int nbk) {
  __shared__ int hist[NBMAX];
  __shared__ float smax[256];
  const int tid = threadIdx.x;

  if (blockIdx.x == 0) {  // fused dtype detect (4096 words of x_prot)
    float m = 0.f;
    for (int i = tid; i < 4096; i += 256) {
      float2 v = bf16x2(xdet[i]);
      float a = fabsf(v.x), b = fabsf(v.y);
      if (!(a <= 1e30f)) a = 1e30f;
      if (!(b <= 1e30f)) b = 1e30f;
      m = fmaxf(m, fmaxf(a, b));
    }
    smax[tid] = m;
    __syncthreads();
    for (int s = 128; s > 0; s >>= 1) {
      if (tid < s) smax[tid] = fmaxf(smax[tid], smax[tid + s]);
      __syncthreads();
    }
    if (tid == 0) *flag = (smax[0] > 1e6f) ? 1 : 0;
  }

  for (int b = tid; b < nbk; b += 256) hist[b] = 0;
  __syncthreads();
  const int e_tot = e_ppi + e_dti;
  const int base = blockIdx.x * 8192;
#pragma unroll 4
  for (int j = 0; j < 32; ++j) {
    int i = base + j * 256 + tid;
    if (i < e_tot) {
      int dst = (i < e_ppi) ? ppi_col[i] : dti_prot[i - e_ppi];
      if ((unsigned)dst < (unsigned)n_prot) atomicAdd(&hist[dst >> 8], 1);
    }
  }
  __syncthreads();
  for (int b = tid; b < nbk; b += 256) {
    int h = hist[b];
    if (h) atomicAdd(&gbh[b], h);
  }
}

// ---------------------------------------------------------------------------
// FAST PATH pass A: partition edges into coarse dst-buckets (256 nodes each).
// Packed entry: src(17b) | type(1b)<<17 | (dst&255)<<18 -> one uint.
// In-block LDS counting sort, then COALESCED copy-out. Bucket bases are
// derived in-block from a scan of gbh (no separate bucket_scan kernel);
// gcur is a zero-based per-bucket allocation cursor.
// ---------------------------------------------------------------------------
__global__ __launch_bounds__(256) void partition_kernel(
    const int* __restrict__ ppi_row, const int* __restrict__ ppi_col,
    const int* __restrict__ dti_drug, const int* __restrict__ dti_prot,
    const int* __restrict__ gbh, int* __restrict__ gcur, uint* __restrict__ P,
    int e_ppi, int e_dti, int n_prot, int nb) {
  __shared__ int hist[NBMAX];
  __shared__ int sh[NBMAX];
  __shared__ int lbase[NBMAX];
  __shared__ int gbase[NBMAX];
  __shared__ int cur[NBMAX];
  __shared__ int totS;
  __shared__ uint entL[TILE_A];    // 16 KB
  __shared__ ushort bktL[TILE_A];  // 8 KB
  const int tid = threadIdx.x;
  const int t2 = tid + 256;
  const int base = blockIdx.x * TILE_A;
  const int e_tot = e_ppi + e_dti;

  hist[tid] = 0;
  hist[t2] = 0;
  __syncthreads();

  uint sv[16];
  int dv[16];
#pragma unroll
  for (int j = 0; j < 16; ++j) {
    int i = base + j * 256 + tid;
    int d = -1;
    uint s = 0;
    if (i < e_tot) {
      int src, dst, type;
      if (i < e_ppi) {
        src = ppi_row[i];
        dst = ppi_col[i];
        type = 0;
      } else {
        int k = i - e_ppi;
        src = dti_drug[k];
        dst = dti_prot[k];
        type = 1;
      }
      if ((unsigned)dst < (unsigned)n_prot) {
        d = dst;
        s = (uint)src | ((uint)type << 17);
        atomicAdd(&hist[dst >> 8], 1);
      }
    }
    sv[j] = s;
    dv[j] = d;
  }
  __syncthreads();

  // inclusive scan of hist (NBMAX slots, 256 threads x 2)
  sh[tid] = hist[tid];
  sh[t2] = hist[t2];
  __syncthreads();
  for (int ofs = 1; ofs < NBMAX; ofs <<= 1) {
    int a0 = (tid >= ofs) ? sh[tid - ofs] : 0;
    int a1 = (t2 >= ofs) ? sh[t2 - ofs] : 0;
    __syncthreads();
    sh[tid] += a0;
    sh[t2] += a1;
    __syncthreads();
  }
  for (int b = tid; b < NBMAX; b += 256) {
    int lb = sh[b] - hist[b];
    lbase[b] = lb;
    cur[b] = lb;
  }
  if (tid == 0) totS = sh[NBMAX - 1];
  __syncthreads();

  // inclusive scan of gbh -> global bucket bases
  sh[tid] = (tid < nb) ? gbh[tid] : 0;
  sh[t2] = (t2 < nb) ? gbh[t2] : 0;
  __syncthreads();
  for (int ofs = 1; ofs < NBMAX; ofs <<= 1) {
    int a0 = (tid >= ofs) ? sh[tid - ofs] : 0;
    int a1 = (t2 >= ofs) ? sh[t2 - ofs] : 0;
    __syncthreads();
    sh[tid] += a0;
    sh[t2] += a1;
    __syncthreads();
  }
  for (int b = tid; b < NBMAX; b += 256) {
    int h = hist[b];
    gbase[b] = h ? ((b ? sh[b - 1] : 0) + atomicAdd(&gcur[b], h)) : 0;
  }
  __syncthreads();

  // scatter into LDS staging, sorted by bucket
#pragma unroll
  for (int j = 0; j < 16; ++j) {
    if (dv[j] >= 0) {
      int b = dv[j] >> 8;
      int r = atomicAdd(&cur[b], 1);
      entL[r] = sv[j] | ((uint)(dv[j] & (NPBK - 1)) << 18);
      bktL[r] = (ushort)b;
    }
  }
  __syncthreads();

  // coalesced copy-out: run of bucket b occupies consecutive u and
  // consecutive global addresses gbase[b] + (u - lbase[b]).
  const int tot = totS;
  for (int u = tid; u < tot; u += 256) {
    int b = bktL[u];
    P[gbase[b] + (u - lbase[b])] = entL[u];
  }
}

// ---------------------------------------------------------------------------
// FAST PATH pass B (fused): one block per bucket.
//  0) scan gbh in LDS -> this bucket's [start,end)
//  1) stream P segment: per-node deg/cnt histogram in LDS
//  2) LDS scan -> per-node offsets; write deg/dinv/invcnt/offsets sequentially
//  3) re-read P (L2-hot), scatter into LDS srt[], stream csr out COALESCED
// ---------------------------------------------------------------------------
__global__ __launch_bounds__(1024) void place_count_kernel(
    const uint* __restrict__ P, const int* __restrict__ gbh,
    uint* __restrict__ csr, int* __restrict__ deg, float* __restrict__ dinv,
    float* __restrict__ invcnt, int* __restrict__ offsets, int n_prot,
    int nbk) {
  __shared__ int degL[NPBK], cntL[NPBK];
  __shared__ int cp[NPBK], cd[NPBK];
  __shared__ int sc[NPBK];
  __shared__ int gsh[NBMAX];
  __shared__ int startS, endS;
  __shared__ uint srt[SEGMAX];  // 32 KB
  const int tid = threadIdx.x;
  const int b = blockIdx.x;
  const int node0 = b * NPBK;
  const int nn = min(NPBK, n_prot - node0);

  // scan gbh -> [start, end) of this bucket
  if (tid < NBMAX) gsh[tid] = (tid < nbk) ? gbh[tid] : 0;
  __syncthreads();
  for (int ofs = 1; ofs < NBMAX; ofs <<= 1) {
    int t = 0;
    if (tid < NBMAX && tid >= ofs) t = gsh[tid - ofs];
    __syncthreads();
    if (tid < NBMAX) gsh[tid] += t;
    __syncthreads();
  }
  if (tid == 0) {
    startS = b ? gsh[b - 1] : 0;
    endS = gsh[b];
  }
  if (tid < NPBK) {
    degL[tid] = 0;
    cntL[tid] = 0;
  }
  __syncthreads();
  const int start = startS, end = endS;
  const int nseg = end - start;

  for (int i = start + tid; i < end; i += 1024) {
    uint p = P[i];
    int nl = (int)(p >> 18);
    if ((p >> 17) & 1u)
      atomicAdd(&cntL[nl], 1);
    else
      atomicAdd(&degL[nl], 1);
  }
  __syncthreads();

  // inclusive scan over per-node totals (256 entries), local 0-based
  int v = 0;
  if (tid < NPBK) {
    v = (tid < nn) ? (degL[tid] + cntL[tid]) : 0;
    sc[tid] = v;
  }
  __syncthreads();
  for (int ofs = 1; ofs < NPBK; ofs <<= 1) {
    int t = 0;
    if (tid < NPBK && tid >= ofs) t = sc[tid - ofs];
    __syncthreads();
    if (tid < NPBK) sc[tid] += t;
    __syncthreads();
  }
  if (tid < nn) {
    int d = degL[tid], c = cntL[tid];
    int lexcl = sc[tid] - v;  // local position within segment
    int node = node0 + tid;
    offsets[node] = start + lexcl;
    deg[node] = d;
    dinv[node] = rsqrtf((float)(d + 1));  // +1 self-loop
    invcnt[node] = 1.0f / fmaxf((float)c, 1.0f);
    cp[tid] = lexcl;
    cd[tid] = lexcl + d;
  }
  if (b == nbk - 1 && tid == 0) offsets[n_prot] = end;
  __syncthreads();

  if (nseg <= SEGMAX) {
    // sort into LDS, then coalesced writeout
    for (int i = start + tid; i < end; i += 1024) {
      uint p = P[i];  // L2-hot re-read
      int nl = (int)(p >> 18);
      int pos =
          ((p >> 17) & 1u) ? atomicAdd(&cd[nl], 1) : atomicAdd(&cp[nl], 1);
      srt[pos] = p & 0x1ffffu;
    }
    __syncthreads();
    for (int u = tid; u < nseg; u += 1024) csr[start + u] = srt[u];
  } else {
    // oversized segment: direct scattered writes (window still L2-resident)
    for (int i = start + tid; i < end; i += 1024) {
      uint p = P[i];
      int nl = (int)(p >> 18);
      int pos =
          ((p >> 17) & 1u) ? atomicAdd(&cd[nl], 1) : atomicAdd(&cp[nl], 1);
      csr[start + pos] = p & 0x1ffffu;
    }
  }
}

// ---------------------------------------------------------------------------
// FALLBACK path kernels (used only when packing guards fail).
// ---------------------------------------------------------------------------
__global__ void count_kernel(const int* __restrict__ ppi_col,
                             const int* __restrict__ dti_prot,
                             int* __restrict__ deg, int* __restrict__ cnt,
                             int e_ppi, int e_dti, int n_prot) {
  int i = blockIdx.x * blockDim.x + threadIdx.x;
  if (i < e_ppi) {
    int c = ppi_col[i];
    if ((unsigned)c < (unsigned)n_prot) atomicAdd(&deg[c], 1);
  } else if (i < e_ppi + e_dti) {
    int c = dti_prot[i - e_ppi];
    if ((unsigned)c < (unsigned)n_prot) atomicAdd(&cnt[c], 1);
  }
}

__global__ void block_sum_kernel(const int* __restrict__ deg,
                                 const int* __restrict__ cnt, int n,
                                 float* __restrict__ dinv,
                                 float* __restrict__ invcnt,
                                 int* __restrict__ bsum) {
  __shared__ int sh[256];
  int i = blockIdx.x * 256 + threadIdx.x;
  int t = 0;
  if (i < n) {
    int d = deg[i], c = cnt[i];
    dinv[i] = rsqrtf((float)(d + 1));  // +1 self-loop
    invcnt[i] = 1.0f / fmaxf((float)c, 1.0f);
    t = d + c;
  }
  sh[threadIdx.x] = t;
  __syncthreads();
  for (int s = 128; s > 0; s >>= 1) {
    if (threadIdx.x < s) sh[threadIdx.x] += sh[threadIdx.x + s];
    __syncthreads();
  }
  if (threadIdx.x == 0) bsum[blockIdx.x] = sh[0];
}

__global__ void scan_bsums_kernel(int* __restrict__ bsum, int nb) {
  __shared__ int sh[1024];
  __shared__ int carry;
  int tid = threadIdx.x;
  if (tid == 0) carry = 0;
  __syncthreads();
  for (int base = 0; base < nb; base += 1024) {
    int i = base + tid;
    int v = (i < nb) ? bsum[i] : 0;
    sh[tid] = v;
    __syncthreads();
    for (int ofs = 1; ofs < 1024; ofs <<= 1) {
      int t = (tid >= ofs) ? sh[tid - ofs] : 0;
      __syncthreads();
      sh[tid] += t;
      __syncthreads();
    }
    if (i < nb) bsum[i] = carry + sh[tid] - v;  // exclusive
    int total = sh[1023];
    __syncthreads();
    if (tid == 0) carry += total;
    __syncthreads();
  }
}

__global__ void scan_final_kernel(const int* __restrict__ deg,
                                  const int* __restrict__ cnt,
                                  const int* __restrict__ bbase,
                                  int* __restrict__ offsets, int n) {
  __shared__ int sh[256];
  int tid = threadIdx.x;
  int i = blockIdx.x * 256 + tid;
  int v = (i < n) ? deg[i] + cnt[i] : 0;
  sh[tid] = v;
  __syncthreads();
  for (int ofs = 1; ofs < 256; ofs <<= 1) {
    int t = (tid >= ofs) ? sh[tid - ofs] : 0;
    __syncthreads();
    sh[tid] += t;
    __syncthreads();
  }
  if (i < n) {
    int excl = bbase[blockIdx.x] + sh[tid] - v;
    offsets[i] = excl;
    if (i == n - 1) offsets[n] = excl + v;
  }
}

__global__ void fill_kernel(const int* __restrict__ ppi_row,
                            const int* __restrict__ ppi_col,
                            const int* __restrict__ dti_drug,
                            const int* __restrict__ dti_prot,
                            const int* __restrict__ offsets,
                            const int* __restrict__ deg,
                            int* __restrict__ fposp, int* __restrict__ fposd,
                            uint* __restrict__ csr, int e_ppi, int e_dti,
                            int n_prot) {
  int i = blockIdx.x * blockDim.x + threadIdx.x;
  if (i < e_ppi) {
    int dst = ppi_col[i];
    if ((unsigned)dst >= (unsigned)n_prot) return;
    int pos = offsets[dst] + atomicAdd(&fposp[dst], 1);
    csr[pos] = (uint)ppi_row[i];
  } else if (i < e_ppi + e_dti) {
    int j = i - e_ppi;
    int dst = dti_prot[j];
    if ((unsigned)dst >= (unsigned)n_prot) return;
    int pos = offsets[dst] + deg[dst] + atomicAdd(&fposd[dst], 1);
    csr[pos] = (uint)dti_drug[j];
  }
}

// ---------------------------------------------------------------------------
// MFMA GEMM bodies (shared LDS buffers passed in). fp32 x handled via hi/lo
// bf16 split (x = hi + lo).
// ---------------------------------------------------------------------------
static __device__ void gemm_prot_body(
    uint4 (*aF)[4][2][64], ushort (*xwl)[128], const void* __restrict__ X,
    const void* __restrict__ Wg, const void* __restrict__ Wp,
    const void* __restrict__ bg, const void* __restrict__ bp,
    const float* __restrict__ dinv, uint* __restrict__ xw2,
    void* __restrict__ outx3, int isf, int M, int bid, int nblk) {
  const int tid = threadIdx.x;
  const int wv = tid >> 6, lane = tid & 63;
  const int cl = lane & 15, kg = lane >> 4;
  const int c = wv * 16 + cl;  // this wave's output column (0..127)

  short8 bG[4], bP[4];
#pragma unroll
  for (int kt = 0; kt < 4; ++kt) {
    int k0 = kt * 32 + 8 * kg;
    short8 fg, fp;
    if (isf) {
      const float* WgF = (const float*)Wg;
      const float* WpF = (const float*)Wp;
#pragma unroll
      for (int j = 0; j < 8; ++j) {
        fg[j] = (short)f2bf(WgF[(k0 + j) * D + c]);
        fp[j] = (short)f2bf(WpF[(k0 + j) * D + c]);
      }
    } else {
      const ushort* WgH = (const ushort*)Wg;
      const ushort* WpH = (const ushort*)Wp;
#pragma unroll
      for (int j = 0; j < 8; ++j) {
        fg[j] = (short)WgH[(k0 + j) * D + c];
        fp[j] = (short)WpH[(k0 + j) * D + c];
      }
    }
    bG[kt] = fg;
    bP[kt] = fp;
  }
  float btc;
  {
    float a = isf ? ((const float*)bg)[c] : bf2f(((const ushort*)bg)[c]);
    float b = isf ? ((const float*)bp)[c] : bf2f(((const ushort*)bp)[c]);
    btc = a + b + 1e-6f;
  }

  for (int row0 = bid * 64; row0 < M; row0 += nblk * 64) {
    for (int u = tid; u < 1024; u += 512) {
      int row = u >> 4, kc = u & 15;
      int grow = row0 + row;
      uint4 hi = make_uint4(0, 0, 0, 0), lo = make_uint4(0, 0, 0, 0);
      if (isf) {
        if (grow < M) {
          const float4* Xf = (const float4*)X;
          float4 v0 = Xf[(size_t)grow * 32 + kc * 2];
          float4 v1 = Xf[(size_t)grow * 32 + kc * 2 + 1];
          float v[8] = {v0.x, v0.y, v0.z, v0.w, v1.x, v1.y, v1.z, v1.w};
          uint hw[4], lw[4];
#pragma unroll
          for (int j = 0; j < 4; ++j) {
            ushort h0 = f2bf(v[2 * j]), h1 = f2bf(v[2 * j + 1]);
            ushort l0 = f2bf(v[2 * j] - bf2f(h0));
            ushort l1 = f2bf(v[2 * j + 1] - bf2f(h1));
            hw[j] = (uint)h0 | ((uint)h1 << 16);
            lw[j] = (uint)l0 | ((uint)l1 << 16);
          }
          hi = make_uint4(hw[0], hw[1], hw[2], hw[3]);
          lo = make_uint4(lw[0], lw[1], lw[2], lw[3]);
        }
      } else {
        if (grow < M) hi = ((const uint4*)X)[(size_t)grow * 16 + kc];
      }
      int ln = (kc & 3) * 16 + (row & 15);
      int g = row >> 4, kt = kc >> 2;
      aF[g][kt][0][ln] = hi;
      if (isf) aF[g][kt][1][ln] = lo;
    }
    __syncthreads();

#pragma unroll
    for (int g = 0; g < 4; ++g) {
      f32x4 accG = {0.f, 0.f, 0.f, 0.f};
      f32x4 accP = {0.f, 0.f, 0.f, 0.f};
      uint4 aH[4];
#pragma unroll
      for (int kt = 0; kt < 4; ++kt) aH[kt] = aF[g][kt][0][lane];
#pragma unroll
      for (int kt = 0; kt < 4; ++kt) {
        short8 a = __builtin_bit_cast(short8, aH[kt]);
        accG = __builtin_amdgcn_mfma_f32_16x16x32_bf16(a, bG[kt], accG, 0, 0, 0);
        accP = __builtin_amdgcn_mfma_f32_16x16x32_bf16(a, bP[kt], accP, 0, 0, 0);
      }
      if (isf) {
        uint4 aL[4];
#pragma unroll
        for (int kt = 0; kt < 4; ++kt) aL[kt] = aF[g][kt][1][lane];
#pragma unroll
        for (int kt = 0; kt < 4; ++kt) {
          short8 a = __builtin_bit_cast(short8, aL[kt]);
          accG = __builtin_amdgcn_mfma_f32_16x16x32_bf16(a, bG[kt], accG, 0, 0, 0);
          accP = __builtin_amdgcn_mfma_f32_16x16x32_bf16(a, bP[kt], accP, 0, 0, 0);
        }
      }
      int rl0 = g * 16 + kg * 4;
#pragma unroll
      for (int r = 0; r < 4; ++r) {
        int row = row0 + rl0 + r;
        if (row < M) {
          float dn = dinv[row];
          float gv = accG[r], pv = accP[r];
          xwl[rl0 + r][c] = f2bf(gv * dn);
          float ov = fmaf(gv, dn * dn, pv + btc);
          if (isf)
            ((float*)outx3)[(size_t)row * D + c] = ov;
          else
            ((ushort*)outx3)[(size_t)row * D + c] = f2bf(ov);
        }
      }
    }
    __syncthreads();

    int valid = min(64, M - row0);
    const uint4* src = (const uint4*)xwl;
    uint4* dst = (uint4*)xw2 + (size_t)row0 * 16;
    for (int u = tid; u < valid * 16; u += 512) dst[u] = src[u];
  }
}

static __device__ void gemm_drug_body(uint4 (*aF)[4][2][64], ushort (*yl)[128],
                                      const void* __restrict__ X,
                                      const void* __restrict__ W,
                                      const void* __restrict__ bias,
                                      uint* __restrict__ Y2, int isf, int M,
                                      int bid, int nblk) {
  const int tid = threadIdx.x;
  const int wv = tid >> 6, lane = tid & 63;
  const int cl = lane & 15, kg = lane >> 4;
  const int c = wv * 16 + cl;

  short8 bT[4];
#pragma unroll
  for (int kt = 0; kt < 4; ++kt) {
    int k0 = kt * 32 + 8 * kg;
    short8 ft;
    if (isf) {
      const float* Wf = (const float*)W;
#pragma unroll
      for (int j = 0; j < 8; ++j) ft[j] = (short)f2bf(Wf[(k0 + j) * D + c]);
    } else {
      const ushort* Wh = (const ushort*)W;
#pragma unroll
      for (int j = 0; j < 8; ++j) ft[j] = (short)Wh[(k0 + j) * D + c];
    }
    bT[kt] = ft;
  }
  float btc = isf ? ((const float*)bias)[c] : bf2f(((const ushort*)bias)[c]);

  for (int row0 = bid * 64; row0 < M; row0 += nblk * 64) {
    for (int u = tid; u < 1024; u += 512) {
      int row = u >> 4, kc = u & 15;
      int grow = row0 + row;
      uint4 hi = make_uint4(0, 0, 0, 0), lo = make_uint4(0, 0, 0, 0);
      if (isf) {
        if (grow < M) {
          const float4* Xf = (const float4*)X;
          float4 v0 = Xf[(size_t)grow * 32 + kc * 2];
          float4 v1 = Xf[(size_t)grow * 32 + kc * 2 + 1];
          float v[8] = {v0.x, v0.y, v0.z, v0.w, v1.x, v1.y, v1.z, v1.w};
          uint hw[4], lw[4];
#pragma unroll
          for (int j = 0; j < 4; ++j) {
            ushort h0 = f2bf(v[2 * j]), h1 = f2bf(v[2 * j + 1]);
            ushort l0 = f2bf(v[2 * j] - bf2f(h0));
            ushort l1 = f2bf(v[2 * j + 1] - bf2f(h1));
            hw[j] = (uint)h0 | ((uint)h1 << 16);
            lw[j] = (uint)l0 | ((uint)l1 << 16);
          }
          hi = make_uint4(hw[0], hw[1], hw[2], hw[3]);
          lo = make_uint4(lw[0], lw[1], lw[2], lw[3]);
        }
      } else {
        if (grow < M) hi = ((const uint4*)X)[(size_t)grow * 16 + kc];
      }
      int ln = (kc & 3) * 16 + (row & 15);
      int g = row >> 4, kt = kc >> 2;
      aF[g][kt][0][ln] = hi;
      if (isf) aF[g][kt][1][ln] = lo;
    }
    __syncthreads();

#pragma unroll
    for (int g = 0; g < 4; ++g) {
      f32x4 acc = {0.f, 0.f, 0.f, 0.f};
      uint4 aH[4];
#pragma unroll
      for (int kt = 0; kt < 4; ++kt) aH[kt] = aF[g][kt][0][lane];
#pragma unroll
      for (int kt = 0; kt < 4; ++kt) {
        short8 a = __builtin_bit_cast(short8, aH[kt]);
        acc = __builtin_amdgcn_mfma_f32_16x16x32_bf16(a, bT[kt], acc, 0, 0, 0);
      }
      if (isf) {
        uint4 aL[4];
#pragma unroll
        for (int kt = 0; kt < 4; ++kt) aL[kt] = aF[g][kt][1][lane];
#pragma unroll
        for (int kt = 0; kt < 4; ++kt) {
          short8 a = __builtin_bit_cast(short8, aL[kt]);
          acc = __builtin_amdgcn_mfma_f32_16x16x32_bf16(a, bT[kt], acc, 0, 0, 0);
        }
      }
      int rl0 = g * 16 + kg * 4;
#pragma unroll
      for (int r = 0; r < 4; ++r) {
        int row = row0 + rl0 + r;
        if (row < M) yl[rl0 + r][c] = f2bf(acc[r] + btc);
      }
    }
    __syncthreads();

    int valid = min(64, M - row0);
    const uint4* src = (const uint4*)yl;
    uint4* dst = (uint4*)Y2 + (size_t)row0 * 16;
    for (int u = tid; u < valid * 16; u += 512) dst[u] = src[u];
  }
}

// Fused GEMM dispatch: blocks [0,gp) = protein, [gp, gp+gd) = drug.
__global__ __launch_bounds__(512) void gemm_fused_kernel(
    const void* __restrict__ Xp, const void* __restrict__ Wg,
    const void* __restrict__ Wp, const void* __restrict__ bg,
    const void* __restrict__ bp, const float* __restrict__ dinv,
    uint* __restrict__ xw2, void* __restrict__ outx3, int Mp, int gp,
    const void* __restrict__ Xd, const void* __restrict__ Wt,
    const void* __restrict__ bt, uint* __restrict__ yd2, int Md,
    const int* __restrict__ flag) {
  __shared__ uint4 aF[4][4][2][64];  // 32 KB
  __shared__ ushort tb[64][128];     // 16 KB
  const int isf = *flag;
  if ((int)blockIdx.x < gp)
    gemm_prot_body(aF, tb, Xp, Wg, Wp, bg, bp, dinv, xw2, outx3, isf, Mp,
                   blockIdx.x, gp);
  else
    gemm_drug_body(aF, tb, Xd, Wt, bt, yd2, isf, Md, blockIdx.x - gp,
                   gridDim.x - gp);
}

// ---------------------------------------------------------------------------
// Gather + LayerNorm v3. One wave per node; four 16-lane groups each gather
// one edge row as 16B dwordx4. PPI and DTI streams UNIFIED into one loop so
// their loads overlap (deeper MLP); per-edge table/scale selected by position
// (per-lane pointer + cndmask scale, folded in via fmaf). x3' read hoisted
// above the gather so it overlaps the edge loads.
// ---------------------------------------------------------------------------
__global__ __launch_bounds__(256) void gather_ln_kernel(
    const uint* __restrict__ xw2, const uint* __restrict__ yd2,
    const float* __restrict__ dinv, const float* __restrict__ invcnt,
    const int* __restrict__ offsets, const int* __restrict__ deg,
    const uint* __restrict__ csr, void* __restrict__ out,
    const int* __restrict__ flag, int n_prot) {
  const int isf = *flag;
  const int node = (blockIdx.x * 256 + threadIdx.x) >> 6;
  const int lane = threadIdx.x & 63;
  const int grp = lane >> 4;  // 0..3 : edge sub-group
  const int li = lane & 15;   // cols [li*8, li*8+8)  (uint4 index li)
  if (node >= n_prot) return;
  const int s0 = offsets[node];
  const int s1 = offsets[node + 1];
  const int sm = s0 + deg[node];
  const float dn = dinv[node], ic = invcnt[node];

  // hoisted x3' read (independent of the gather loop; overlaps edge loads)
  float x3l[8];
  if (isf) {
    const float4* xr = (const float4*)out + (size_t)node * 32 + li * 2;
    float4 x0 = xr[0], x1 = xr[1];
    x3l[0] = x0.x; x3l[1] = x0.y; x3l[2] = x0.z; x3l[3] = x0.w;
    x3l[4] = x1.x; x3l[5] = x1.y; x3l[6] = x1.z; x3l[7] = x1.w;
  } else {
    uint4 xr = ((const uint4*)out)[(size_t)node * 16 + li];
    float2 t0 = bf16x2(xr.x), t1 = bf16x2(xr.y);
    float2 t2 = bf16x2(xr.z), t3 = bf16x2(xr.w);
    x3l[0] = t0.x; x3l[1] = t0.y; x3l[2] = t1.x; x3l[3] = t1.y;
    x3l[4] = t2.x; x3l[5] = t2.y; x3l[6] = t3.x; x3l[7] = t3.y;
  }

  float acc[8] = {0.f, 0.f, 0.f, 0.f, 0.f, 0.f, 0.f, 0.f};
  const uint4* X4 = (const uint4*)xw2;
  const uint4* Y4 = (const uint4*)yd2;

  for (int base = s0; base < s1;) {
    int m = min(64, s1 - base);
    uint ent = (lane < m) ? csr[base + lane] : 0u;
    int nq = m >> 2;  // full quads of 4 edges
    int t = 0;
    for (; t + 4 <= nq; t += 4) {  // 16 edges; 4 loads in flight per lane
      uint4 w[4];
      float sc[4];
#pragma unroll
      for (int q = 0; q < 4; ++q) {
        int slot = (t + q) * 4 + grp;
        uint e = __shfl(ent, slot);
        bool isP = (base + slot) < sm;
        const uint4* T = isP ? X4 : Y4;
        w[q] = T[(size_t)e * 16 + li];
        sc[q] = isP ? dn : ic;
      }
#pragma unroll
      for (int q = 0; q < 4; ++q) facc8(acc, w[q], sc[q]);
    }
    for (; t + 2 <= nq; t += 2) {
      uint4 w0, w1;
      float sc0, sc1;
      {
        int slot = t * 4 + grp;
        uint e = __shfl(ent, slot);
        bool isP = (base + slot) < sm;
        const uint4* T = isP ? X4 : Y4;
        w0 = T[(size_t)e * 16 + li];
        sc0 = isP ? dn : ic;
      }
      {
        int slot = (t + 1) * 4 + grp;
        uint e = __shfl(ent, slot);
        bool isP = (base + slot) < sm;
        const uint4* T = isP ? X4 : Y4;
        w1 = T[(size_t)e * 16 + li];
        sc1 = isP ? dn : ic;
      }
      facc8(acc, w0, sc0);
      facc8(acc, w1, sc1);
    }
    for (; t < nq; ++t) {
      int slot = t * 4 + grp;
      uint e = __shfl(ent, slot);
      bool isP = (base + slot) < sm;
      const uint4* T = isP ? X4 : Y4;
      uint4 wv = T[(size_t)e * 16 + li];
      facc8(acc, wv, isP ? dn : ic);
    }
    int rem = m & 3;
    if (rem) {
      int slot = nq * 4 + grp;
      uint e = __shfl(ent, slot);
      if (grp < rem) {
        bool isP = (base + slot) < sm;
        const uint4* T = isP ? X4 : Y4;
        uint4 wv = T[(size_t)e * 16 + li];
        facc8(acc, wv, isP ? dn : ic);
      }
    }
    base += m;
  }

  // reduce across the 4 groups (lanes ^16, ^32), add x3'
  float v[8];
#pragma unroll
  for (int i = 0; i < 8; ++i) {
    float t = acc[i];
    t += __shfl_xor(t, 16);
    t += __shfl_xor(t, 32);
    v[i] = t + x3l[i];
  }

  // LayerNorm over 128 cols (each li owns 8; reduce over 16 lanes)
  float s = 0.f, ss = 0.f;
#pragma unroll
  for (int i = 0; i < 8; ++i) {
    s += v[i];
    ss = fmaf(v[i], v[i], ss);
  }
#pragma unroll
  for (int off = 1; off < 16; off <<= 1) {
    s += __shfl_xor(s, off);
    ss += __shfl_xor(ss, off);
  }
  float mu = s * (1.0f / 128.0f);
  float var = ss * (1.0f / 128.0f) - mu * mu;
  float rs = rsqrtf(var + 1e-5f);
#pragma unroll
  for (int i = 0; i < 8; ++i) v[i] = (v[i] - mu) * rs;

  if (isf) {
    if (grp < 2) {  // 32 lanes cover the 512B row
      float4 o = (grp == 0) ? make_float4(v[0], v[1], v[2], v[3])
                            : make_float4(v[4], v[5], v[6], v[7]);
      ((float4*)out)[(size_t)node * 32 + li * 2 + grp] = o;
    }
  } else {
    if (grp == 0) {
      uint4 o;
      o.x = pack_bf16x2(v[0], v[1]);
      o.y = pack_bf16x2(v[2], v[3]);
      o.z = pack_bf16x2(v[4], v[5]);
      o.w = pack_bf16x2(v[6], v[7]);
      ((uint4*)out)[(size_t)node * 16 + li] = o;
    }
  }
}

// ---------------------------------------------------------------------------
extern "C" void kernel_launch(void* const* d_in, const int* in_sizes, int n_in,
                              void* d_out, int out_size, void* d_ws,
                              size_t ws_size, hipStream_t stream) {
  const void* x_prot = d_in[0];
  const void* x_drug = d_in[1];
  const void* W_gcn = d_in[2];
  const void* b_gcn = d_in[3];
  const void* W_td = d_in[4];
  const void* b_td = d_in[5];
  const void* W_pr = d_in[6];
  const void* b_pr = d_in[7];
  const int* ppi = (const int*)d_in[8];
  const int* dti_drug = (const int*)d_in[9];
  const int* dti_prot = (const int*)d_in[10];

  int n_prot = in_sizes[0] / D;
  int n_drug = in_sizes[1] / D;
  int e_ppi = in_sizes[8] / 2;
  int e_dti = in_sizes[9];
  int e_tot = e_ppi + e_dti;
  int nb = (n_prot + 255) / 256;
  int nbk = (n_prot + NPBK - 1) / NPBK;  // coarse buckets (== nb here)

  char* ws = (char*)d_ws;
  size_t off = 0;
  auto alloc = [&](size_t bytes) {
    void* p = ws + off;
    off = (off + bytes + 255) & ~(size_t)255;
    return p;
  };
  int* flag = (int*)alloc(256);
  uint* xw2 = (uint*)alloc((size_t)n_prot * 64 * 4);  // 25.6 MB (pre-scaled)
  uint* yd2 = (uint*)alloc((size_t)n_drug * 64 * 4);  //  5.1 MB
  int* deg = (int*)alloc((size_t)n_prot * 4);
  int* cnt = (int*)alloc((size_t)n_prot * 4);
  float* dinv = (float*)alloc((size_t)n_prot * 4);
  float* invcnt = (float*)alloc((size_t)n_prot * 4);
  int* offsets = (int*)alloc((size_t)(n_prot + 1) * 4);
  int* fposp = (int*)alloc((size_t)n_prot * 4);
  int* fposd = (int*)alloc((size_t)n_prot * 4);
  int* bsum = (int*)alloc((size_t)nb * 4);
  int* gbh = (int*)alloc((size_t)NBMAX * 4);   // bucket totals
  int* gcur = (int*)alloc((size_t)NBMAX * 4);  // zero-based alloc cursors
  uint* csr = (uint*)alloc((size_t)e_tot * 4);  // 9.6 MB

  if (off > ws_size) return;  // insufficient workspace: bail cleanly

  // Partitioned-edge scratch aliases xw2: place_count finishes before
  // gemm writes xw2 (same stream), and e_tot*4 <= n_prot*256 here.
  uint* P = xw2;
  bool fast_fill = (n_prot <= (1 << 17)) && (n_drug <= (1 << 17)) &&
                   (nbk <= NBMAX) && ((size_t)e_tot * 4 <= (size_t)n_prot * 256);

  if (fast_fill) {
    // gbh and gcur are adjacent 2KB allocations -> one 4KB memset
    hipMemsetAsync(gbh, 0, (size_t)2 * NBMAX * 4, stream);
    bucket_hist_kernel<<<(e_tot + 8191) / 8192, 256, 0, stream>>>(
        ppi + e_ppi, dti_prot, gbh, (const uint*)x_prot, flag, e_ppi, e_dti,
        n_prot, nbk);
    partition_kernel<<<(e_tot + TILE_A - 1) / TILE_A, 256, 0, stream>>>(
        ppi, ppi + e_ppi, dti_drug, dti_prot, gbh, gcur, P, e_ppi, e_dti,
        n_prot, nbk);
    place_count_kernel<<<nbk, 1024, 0, stream>>>(
        P, gbh, csr, deg, dinv, invcnt, offsets, n_prot, nbk);
  } else {
    detect_kernel<<<1, 256, 0, stream>>>((const uint*)x_prot, 4096, flag);
    hipMemsetAsync(deg, 0, (size_t)n_prot * 4, stream);
    hipMemsetAsync(cnt, 0, (size_t)n_prot * 4, stream);
    hipMemsetAsync(fposp, 0, (size_t)n_prot * 4, stream);
    hipMemsetAsync(fposd, 0, (size_t)n_prot * 4, stream);
    count_kernel<<<(e_tot + 255) / 256, 256, 0, stream>>>(
        ppi + e_ppi, dti_prot, deg, cnt, e_ppi, e_dti, n_prot);
    block_sum_kernel<<<nb, 256, 0, stream>>>(deg, cnt, n_prot, dinv, invcnt,
                                             bsum);
    scan_bsums_kernel<<<1, 1024, 0, stream>>>(bsum, nb);
    scan_final_kernel<<<nb, 256, 0, stream>>>(deg, cnt, bsum, offsets, n_prot);
    fill_kernel<<<(e_tot + 255) / 256, 256, 0, stream>>>(
        ppi, ppi + e_ppi, dti_drug, dti_prot, offsets, deg, fposp, fposd, csr,
        e_ppi, e_dti, n_prot);
  }

  int nbat_p = (n_prot + 63) / 64;
  int grid_p = nbat_p < 512 ? nbat_p : 512;
  int nbat_d = (n_drug + 63) / 64;
  int grid_d = nbat_d < 512 ? nbat_d : 512;
  gemm_fused_kernel<<<grid_p + grid_d, 512, 0, stream>>>(
      x_prot, W_gcn, W_pr, b_gcn, b_pr, dinv, xw2, d_out, n_prot, grid_p,
      x_drug, W_td, b_td, yd2, n_drug, flag);

  gather_ln_kernel<<<(n_prot + 3) / 4, 256, 0, stream>>>(
      xw2, yd2, dinv, invcnt, offsets, deg, csr, d_out, flag, n_prot);
}